// Round 3
// baseline (367.800 us; speedup 1.0000x reference)
//
#include <hip/hip_runtime.h>

// ============================================================================
// ETC layer: windowed rel-pos attention + FFN, bf16 MFMA GEMMs on gfx950
//   B=2 S=2048 D_MODEL=1024 NHEAD=16 DHEAD=64 DFF=4096 R=25 W=51 K=5
// R3: gemm_bt upgraded to global_load_lds width-16 staging (m97 structure)
// ============================================================================

#define D_MODEL 1024
#define SEQ     2048
#define NROWS   4096      // B*S
#define WIN     51
#define RAD     25

typedef __attribute__((ext_vector_type(8))) __bf16 bf16x8;
typedef __attribute__((ext_vector_type(4))) float  floatx4;

__device__ __forceinline__ unsigned short f2bf(float x) {
    unsigned u = __float_as_uint(x);
    unsigned r = u + 0x7fffu + ((u >> 16) & 1u);
    return (unsigned short)(r >> 16);
}
__device__ __forceinline__ float bf2f(unsigned short h) {
    return __uint_as_float(((unsigned)h) << 16);
}

// async global->LDS 16B per lane; LDS dest = wave-uniform base + lane*16
__device__ __forceinline__ void gld16(const unsigned short* g, unsigned short* l) {
    __builtin_amdgcn_global_load_lds(
        (const __attribute__((address_space(1))) unsigned int*)g,
        (__attribute__((address_space(3))) unsigned int*)l,
        16, 0, 0);
}

// ---------------------------------------------------------------------------
__global__ __launch_bounds__(256) void cvt4(const float* __restrict__ in,
                                            unsigned short* __restrict__ out,
                                            int n4) {
    int i = blockIdx.x * 256 + threadIdx.x;
    if (i >= n4) return;
    float4 f = ((const float4*)in)[i];
    ushort4 u;
    u.x = f2bf(f.x); u.y = f2bf(f.y); u.z = f2bf(f.z); u.w = f2bf(f.w);
    ((ushort4*)out)[i] = u;
}

__global__ __launch_bounds__(256) void concat3(const float* __restrict__ a,
                                               const float* __restrict__ b,
                                               const float* __restrict__ c,
                                               float* __restrict__ out) {
    int i = blockIdx.x * 256 + threadIdx.x;   // 3072 total
    if (i >= 3072) return;
    float v = (i < 1024) ? a[i] : (i < 2048 ? b[i - 1024] : c[i - 2048]);
    out[i] = v;
}

// ---------------------------------------------------------------------------
// GEMM  C[M,N] = A[M,K] @ W[N,K]^T + bias   (bf16 in, fp32 acc)
// 128x128 tile, 4 waves, 16x16x32 MFMA. Staging via global_load_lds x16
// (m97 structure). LDS tiles MUST stay unpadded row-major BK=32:
// chunk c (16B) = (row=c>>2, col8=(c&3)*8); wave w owns chunks [128w,128w+128).
// ---------------------------------------------------------------------------
#define BM 128
#define BN 128
#define BK 32

__global__ __launch_bounds__(256, 2)
void gemm_bt(const unsigned short* __restrict__ A,
             const unsigned short* __restrict__ Wt,
             const float* __restrict__ bias,
             float* __restrict__ Cf,
             unsigned short* __restrict__ Cb,
             int K, int ldc, int relu)
{
    __shared__ __attribute__((aligned(16))) unsigned short As[BM * BK];
    __shared__ __attribute__((aligned(16))) unsigned short Bs[BN * BK];

    const int tid  = threadIdx.x;
    const int lane = tid & 63;
    const int wave = tid >> 6;
    const int bm = blockIdx.y * BM;
    const int bn = blockIdx.x * BN;
    const int wm = (wave >> 1) * 64;
    const int wn = (wave & 1) * 64;

    // staging chunk for this lane (issue 0); issue 1 is +64 chunks = +16 rows
    const int c0   = wave * 128 + lane;
    const int srow = c0 >> 2;
    const int scol = (c0 & 3) * 8;
    const unsigned short* Ag = A  + (size_t)(bm + srow) * K + scol;
    const unsigned short* Wg = Wt + (size_t)(bn + srow) * K + scol;
    const size_t rstep = (size_t)16 * K;   // +64 chunks
    unsigned short* lA = As + wave * 1024; // chunk base (elems): wave*128*8
    unsigned short* lB = Bs + wave * 1024;

    const int fm  = lane & 15;
    const int fk  = (lane >> 4) * 8;

    floatx4 acc[4][4] = {};

    for (int k0 = 0; k0 < K; k0 += BK) {
        __syncthreads();   // prev iter's frag reads done before overwrite
        gld16(Ag + k0,         lA);
        gld16(Ag + k0 + rstep, lA + 512);
        gld16(Wg + k0,         lB);
        gld16(Wg + k0 + rstep, lB + 512);
        __syncthreads();   // drains vmcnt -> tiles resident

        bf16x8 af[4], bf[4];
        #pragma unroll
        for (int i = 0; i < 4; i++)
            af[i] = *(const bf16x8*)(As + (wm + i * 16 + fm) * BK + fk);
        #pragma unroll
        for (int j = 0; j < 4; j++)
            bf[j] = *(const bf16x8*)(Bs + (wn + j * 16 + fm) * BK + fk);
        #pragma unroll
        for (int i = 0; i < 4; i++)
            #pragma unroll
            for (int j = 0; j < 4; j++)
                acc[i][j] = __builtin_amdgcn_mfma_f32_16x16x32_bf16(
                    af[i], bf[j], acc[i][j], 0, 0, 0);
    }

    const int r0 = bm + wm + (lane >> 4) * 4;
    const int c0e = bn + wn + (lane & 15);
    #pragma unroll
    for (int i = 0; i < 4; i++) {
        #pragma unroll
        for (int j = 0; j < 4; j++) {
            const int col = c0e + j * 16;
            const float bv = bias[col];
            #pragma unroll
            for (int r = 0; r < 4; r++) {
                const int row = r0 + i * 16 + r;
                float v = acc[i][j][r] + bv;
                if (relu) v = fmaxf(v, 0.0f);
                if (Cf) Cf[(size_t)row * ldc + col] = v;
                if (Cb) Cb[(size_t)row * ldc + col] = f2bf(v);
            }
        }
    }
}

// ---------------------------------------------------------------------------
// Banded MFMA windowed attention (unchanged from R2).
// ---------------------------------------------------------------------------
__global__ __launch_bounds__(256, 2)
void attn_mfma(const unsigned short* __restrict__ qkv,   // (B*S) x 3072 bf16
               const float* __restrict__ rel,            // 11 x 64 fp32
               unsigned short* __restrict__ attnb)       // (B*S) x 1024 bf16
{
    __shared__ __attribute__((aligned(16))) unsigned short Qs[64 * 72];
    __shared__ __attribute__((aligned(16))) unsigned short Ks[128 * 72];
    __shared__ __attribute__((aligned(16))) unsigned short Vt[64 * 168];
    __shared__ __attribute__((aligned(16))) unsigned short Rs[16 * 72];
    __shared__ __attribute__((aligned(16))) unsigned short Pl[4 * 16 * 104];
    __shared__ float Qrl[4 * 16 * 12];

    const int t   = threadIdx.x;
    const int blk = blockIdx.x;          // ((b*16 + h)*32 + st)
    const int st  = blk & 31;
    const int h   = (blk >> 5) & 15;
    const int b   = blk >> 9;
    const int s0  = st << 6;
    const int brow0 = b * SEQ;

    const int trow = t >> 3;             // 0..31
    const int tc   = (t & 7) * 8;        // 0,8,..,56
    const uint4 z4 = make_uint4(0, 0, 0, 0);

    #pragma unroll
    for (int p = 0; p < 2; p++) {        // Q: 64 x 64
        int r = trow + p * 32;
        uint4 v = *(const uint4*)(qkv + (size_t)(brow0 + s0 + r) * 3072 + h * 64 + tc);
        *(uint4*)(Qs + r * 72 + tc) = v;
    }
    #pragma unroll
    for (int p = 0; p < 4; p++) {        // K + V(transposed): 128 band rows
        int kr = trow + p * 32;
        int ka = s0 - 25 + kr;
        bool in = (ka >= 0) & (ka < SEQ);
        uint4 kv = z4, vv = z4;
        if (in) {
            kv = *(const uint4*)(qkv + (size_t)(brow0 + ka) * 3072 + 1024 + h * 64 + tc);
            vv = *(const uint4*)(qkv + (size_t)(brow0 + ka) * 3072 + 2048 + h * 64 + tc);
        }
        *(uint4*)(Ks + kr * 72 + tc) = kv;
        const unsigned short* e = (const unsigned short*)&vv;
        #pragma unroll
        for (int j = 0; j < 8; j++)
            Vt[(tc + j) * 168 + kr] = e[j];
    }
    if (t < 176) {
        float4 f = ((const float4*)rel)[t];
        int fi = t * 4, rr = fi >> 6, cc = fi & 63;
        ushort4 u;
        u.x = f2bf(f.x); u.y = f2bf(f.y); u.z = f2bf(f.z); u.w = f2bf(f.w);
        *(ushort4*)(Rs + rr * 72 + cc) = u;
    } else {
        int fi = 704 + (t - 176) * 4, rr = fi >> 6, cc = fi & 63;
        *(ushort4*)(Rs + rr * 72 + cc) = make_ushort4(0, 0, 0, 0);
    }
    {
        int n = t * 4, w2 = n >> 8, rem = n & 255, rr = rem >> 4, cc = 80 + (rem & 15);
        *(ushort4*)(Pl + w2 * (16 * 104) + rr * 104 + cc) = make_ushort4(0, 0, 0, 0);
    }
    for (int idx = t; idx < 320; idx += 256) {
        int r = idx / 5, cchunk = idx % 5;
        *(uint4*)(Vt + r * 168 + 128 + cchunk * 8) = z4;
    }
    __syncthreads();

    const int wave = t >> 6;
    const int lane = t & 63;
    const int fm   = lane & 15;
    const int fk8  = (lane >> 4) * 8;
    const int S0w  = s0 + wave * 16;
    unsigned short* Plw = Pl + wave * (16 * 104);
    float* Ql = Qrl + wave * (16 * 12);

    bf16x8 qa0 = *(const bf16x8*)(Qs + (wave * 16 + fm) * 72 + fk8);
    bf16x8 qa1 = *(const bf16x8*)(Qs + (wave * 16 + fm) * 72 + fk8 + 32);

    floatx4 Sc[5];
    #pragma unroll
    for (int nt = 0; nt < 5; nt++) {
        bf16x8 kb0 = *(const bf16x8*)(Ks + (wave * 16 + nt * 16 + fm) * 72 + fk8);
        bf16x8 kb1 = *(const bf16x8*)(Ks + (wave * 16 + nt * 16 + fm) * 72 + fk8 + 32);
        floatx4 acc = {0.f, 0.f, 0.f, 0.f};
        acc = __builtin_amdgcn_mfma_f32_16x16x32_bf16(qa0, kb0, acc, 0, 0, 0);
        acc = __builtin_amdgcn_mfma_f32_16x16x32_bf16(qa1, kb1, acc, 0, 0, 0);
        Sc[nt] = acc;
    }
    {
        bf16x8 rb0 = *(const bf16x8*)(Rs + fm * 72 + fk8);
        bf16x8 rb1 = *(const bf16x8*)(Rs + fm * 72 + fk8 + 32);
        floatx4 qr = {0.f, 0.f, 0.f, 0.f};
        qr = __builtin_amdgcn_mfma_f32_16x16x32_bf16(qa0, rb0, qr, 0, 0, 0);
        qr = __builtin_amdgcn_mfma_f32_16x16x32_bf16(qa1, rb1, qr, 0, 0, 0);
        if (fm < 12) {
            #pragma unroll
            for (int reg = 0; reg < 4; reg++)
                Ql[((lane >> 4) * 4 + reg) * 12 + fm] = qr[reg];
        }
    }

    float inv[4];
    const int iq0 = (lane >> 4) * 4;
    #pragma unroll
    for (int reg = 0; reg < 4; reg++) {
        const int i = iq0 + reg;
        float sc[5];
        float mx = -1e30f;
        #pragma unroll
        for (int nt = 0; nt < 5; nt++) {
            int c   = nt * 16 + fm;
            int off = c - 25 - i;
            int ka  = S0w - 25 + c;
            bool valid = (off >= -RAD) & (off <= RAD) & (ka >= 0) & (ka < SEQ);
            int rid = min(max(off, -5), 5) + 5;
            float v = valid ? (Sc[nt][reg] + Ql[i * 12 + rid]) * 0.125f : -1e30f;
            sc[nt] = v;
            mx = fmaxf(mx, v);
        }
        #pragma unroll
        for (int o = 1; o < 16; o <<= 1) mx = fmaxf(mx, __shfl_xor(mx, o));
        float sum = 0.f;
        #pragma unroll
        for (int nt = 0; nt < 5; nt++) {
            float e = __expf(sc[nt] - mx);
            sum += e;
            Plw[i * 104 + nt * 16 + fm] = f2bf(e);
        }
        #pragma unroll
        for (int o = 1; o < 16; o <<= 1) sum += __shfl_xor(sum, o);
        inv[reg] = 1.0f / sum;
    }

    floatx4 O[4] = {};
    #pragma unroll
    for (int kc = 0; kc < 3; kc++) {
        bf16x8 pa = *(const bf16x8*)(Plw + fm * 104 + fk8 + kc * 32);
        #pragma unroll
        for (int nt = 0; nt < 4; nt++) {
            bf16x8 vb = *(const bf16x8*)(Vt + (nt * 16 + fm) * 168 + wave * 16 + fk8 + kc * 32);
            O[nt] = __builtin_amdgcn_mfma_f32_16x16x32_bf16(pa, vb, O[nt], 0, 0, 0);
        }
    }

    #pragma unroll
    for (int nt = 0; nt < 4; nt++) {
        const int d = nt * 16 + fm;
        #pragma unroll
        for (int reg = 0; reg < 4; reg++) {
            const int i = iq0 + reg;
            attnb[(size_t)(brow0 + S0w + i) * 1024 + h * 64 + d] = f2bf(O[nt][reg] * inv[reg]);
        }
    }
}

// ---------------------------------------------------------------------------
// Fused residual + LayerNorm (unchanged)
// ---------------------------------------------------------------------------
__global__ __launch_bounds__(256)
void ln_fuse(const float* __restrict__ af,
             const unsigned short* __restrict__ ab,
             const float* __restrict__ bres,
             const float* __restrict__ gamma,
             const float* __restrict__ beta,
             float* __restrict__ outf,
             unsigned short* __restrict__ outb)
{
    const int wave = threadIdx.x >> 6;
    const int lane = threadIdx.x & 63;
    const int row = blockIdx.x * 4 + wave;
    const size_t base = (size_t)row * D_MODEL;

    float x[16];
    float sum = 0.0f, sq = 0.0f;
    #pragma unroll
    for (int i = 0; i < 4; i++) {
        const int c4 = lane + i * 64;
        float4 vb = ((const float4*)(bres + base))[c4];
        float4 va;
        if (af) {
            va = ((const float4*)(af + base))[c4];
        } else {
            ushort4 ua = ((const ushort4*)(ab + base))[c4];
            va.x = bf2f(ua.x); va.y = bf2f(ua.y); va.z = bf2f(ua.z); va.w = bf2f(ua.w);
        }
        float e0 = va.x + vb.x, e1 = va.y + vb.y, e2 = va.z + vb.z, e3 = va.w + vb.w;
        x[i*4+0] = e0; x[i*4+1] = e1; x[i*4+2] = e2; x[i*4+3] = e3;
        sum += e0 + e1 + e2 + e3;
        sq  += e0*e0 + e1*e1 + e2*e2 + e3*e3;
    }
    #pragma unroll
    for (int off = 32; off > 0; off >>= 1) {
        sum += __shfl_xor(sum, off);
        sq  += __shfl_xor(sq,  off);
    }
    const float mean = sum * (1.0f / 1024.0f);
    const float var  = sq  * (1.0f / 1024.0f) - mean * mean;
    const float rs   = rsqrtf(var + 1e-5f);

    #pragma unroll
    for (int i = 0; i < 4; i++) {
        const int c4 = lane + i * 64;
        float4 g4 = ((const float4*)gamma)[c4];
        float4 b4 = ((const float4*)beta)[c4];
        float4 o;
        o.x = (x[i*4+0] - mean) * rs * g4.x + b4.x;
        o.y = (x[i*4+1] - mean) * rs * g4.y + b4.y;
        o.z = (x[i*4+2] - mean) * rs * g4.z + b4.z;
        o.w = (x[i*4+3] - mean) * rs * g4.w + b4.w;
        if (outf) ((float4*)(outf + base))[c4] = o;
        if (outb) {
            ushort4 u;
            u.x = f2bf(o.x); u.y = f2bf(o.y); u.z = f2bf(o.z); u.w = f2bf(o.w);
            ((ushort4*)(outb + base))[c4] = u;
        }
    }
}

// ---------------------------------------------------------------------------
extern "C" void kernel_launch(void* const* d_in, const int* in_sizes, int n_in,
                              void* d_out, int out_size, void* d_ws, size_t ws_size,
                              hipStream_t stream)
{
    const float* src = (const float*)d_in[0];
    const float* wq  = (const float*)d_in[1];
    const float* bq  = (const float*)d_in[2];
    const float* wk  = (const float*)d_in[3];
    const float* bk  = (const float*)d_in[4];
    const float* wv  = (const float*)d_in[5];
    const float* bv  = (const float*)d_in[6];
    const float* wo  = (const float*)d_in[7];
    const float* bo  = (const float*)d_in[8];
    const float* rel = (const float*)d_in[9];
    const float* w1  = (const float*)d_in[10];
    const float* b1  = (const float*)d_in[11];
    const float* w2  = (const float*)d_in[12];
    const float* b2  = (const float*)d_in[13];
    const float* g1  = (const float*)d_in[14];
    const float* be1 = (const float*)d_in[15];
    const float* g2  = (const float*)d_in[16];
    const float* be2 = (const float*)d_in[17];
    float* out = (float*)d_out;

    char* ws = (char*)d_ws;
    const size_t MB = 1048576;
    unsigned short* wqkvb = (unsigned short*)(ws + 0);        //  6 MB
    unsigned short* wob   = (unsigned short*)(ws + 6  * MB);  //  2 MB
    unsigned short* w1b   = (unsigned short*)(ws + 8  * MB);  //  8 MB
    unsigned short* w2b   = (unsigned short*)(ws + 16 * MB);  //  8 MB
    float*          bqkv  = (float*)         (ws + 24 * MB);  // 12 KB
    unsigned short* xb    = (unsigned short*)(ws + 25 * MB);  //  8 MB (dead after QKV)
    unsigned short* attnb = (unsigned short*)(ws + 25 * MB);  //  reuse xb
    unsigned short* qkvb  = (unsigned short*)(ws + 33 * MB);  // 24 MB (dead after attn)
    unsigned short* ff1b  = (unsigned short*)(ws + 33 * MB);  // 32 MB, reuse
    float*          z     = (float*)         (ws + 65 * MB);  // 16 MB (dead after LN1)
    float*          ff2   = (float*)         (ws + 65 * MB);  //  reuse z
    unsigned short* x1b   = (unsigned short*)(ws + 81 * MB);  //  8 MB

    cvt4<<<4096, 256, 0, stream>>>(src, xb, 1048576);
    cvt4<<<1024, 256, 0, stream>>>(wq, wqkvb,           262144);
    cvt4<<<1024, 256, 0, stream>>>(wk, wqkvb + 1048576, 262144);
    cvt4<<<1024, 256, 0, stream>>>(wv, wqkvb + 2097152, 262144);
    cvt4<<<1024, 256, 0, stream>>>(wo, wob, 262144);
    cvt4<<<4096, 256, 0, stream>>>(w1, w1b, 1048576);
    cvt4<<<4096, 256, 0, stream>>>(w2, w2b, 1048576);
    concat3<<<12, 256, 0, stream>>>(bq, bk, bv, bqkv);

    const dim3 blk(256);
    gemm_bt<<<dim3(3072 / BN, NROWS / BM), blk, 0, stream>>>(
        xb, wqkvb, bqkv, nullptr, qkvb, 1024, 3072, 0);
    attn_mfma<<<1024, blk, 0, stream>>>(qkvb, rel, attnb);
    gemm_bt<<<dim3(1024 / BN, NROWS / BM), blk, 0, stream>>>(
        attnb, wob, bo, z, nullptr, 1024, 1024, 0);
    ln_fuse<<<NROWS / 4, blk, 0, stream>>>(src, nullptr, z, g1, be1, nullptr, x1b);
    gemm_bt<<<dim3(4096 / BN, NROWS / BM), blk, 0, stream>>>(
        x1b, w1b, b1, nullptr, ff1b, 1024, 4096, 1);
    gemm_bt<<<dim3(1024 / BN, NROWS / BM), blk, 0, stream>>>(
        ff1b, w2b, b2, ff2, nullptr, 4096, 1024, 0);
    ln_fuse<<<NROWS / 4, blk, 0, stream>>>(nullptr, x1b, ff2, g2, be2, out, nullptr);
}

// Round 4
// 355.542 us; speedup vs baseline: 1.0345x; 1.0345x over previous
//
#include <hip/hip_runtime.h>

// ============================================================================
// ETC layer: windowed rel-pos attention + FFN, bf16 MFMA GEMMs on gfx950
//   B=2 S=2048 D_MODEL=1024 NHEAD=16 DHEAD=64 DFF=4096 R=25 W=51 K=5
// R4: gemm_bt -> BK=64, double-buffered LDS (1 barrier/iter, prefetch dist 1),
//     XOR-swizzled LDS granules (conflict-free ds_read_b128 under the
//     global_load_lds contiguous-dest constraint).
// ============================================================================

#define D_MODEL 1024
#define SEQ     2048
#define NROWS   4096      // B*S
#define WIN     51
#define RAD     25

typedef __attribute__((ext_vector_type(8))) __bf16 bf16x8;
typedef __attribute__((ext_vector_type(4))) float  floatx4;

__device__ __forceinline__ unsigned short f2bf(float x) {
    unsigned u = __float_as_uint(x);
    unsigned r = u + 0x7fffu + ((u >> 16) & 1u);
    return (unsigned short)(r >> 16);
}
__device__ __forceinline__ float bf2f(unsigned short h) {
    return __uint_as_float(((unsigned)h) << 16);
}

// async global->LDS 16B per lane; LDS dest = wave-uniform base + lane*16
__device__ __forceinline__ void gld16(const unsigned short* g, unsigned short* l) {
    __builtin_amdgcn_global_load_lds(
        (const __attribute__((address_space(1))) unsigned int*)g,
        (__attribute__((address_space(3))) unsigned int*)l,
        16, 0, 0);
}

// ---------------------------------------------------------------------------
__global__ __launch_bounds__(256) void cvt4(const float* __restrict__ in,
                                            unsigned short* __restrict__ out,
                                            int n4) {
    int i = blockIdx.x * 256 + threadIdx.x;
    if (i >= n4) return;
    float4 f = ((const float4*)in)[i];
    ushort4 u;
    u.x = f2bf(f.x); u.y = f2bf(f.y); u.z = f2bf(f.z); u.w = f2bf(f.w);
    ((ushort4*)out)[i] = u;
}

__global__ __launch_bounds__(256) void concat3(const float* __restrict__ a,
                                               const float* __restrict__ b,
                                               const float* __restrict__ c,
                                               float* __restrict__ out) {
    int i = blockIdx.x * 256 + threadIdx.x;   // 3072 total
    if (i >= 3072) return;
    float v = (i < 1024) ? a[i] : (i < 2048 ? b[i - 1024] : c[i - 2048]);
    out[i] = v;
}

// ---------------------------------------------------------------------------
// GEMM  C[M,N] = A[M,K] @ W[N,K]^T + bias   (bf16 in, fp32 acc)
// 128x128 tile, 4 waves (64x64 quadrants), 16x16x32 MFMA, BK=64.
// Double-buffered LDS; per-iter: barrier (vmcnt drain of cur buf) -> issue
// prefetch of next buf -> compute cur. Prefetch latency overlaps compute.
// LDS layout (per operand, per buf): 128 rows x 8 granules (16B each),
// physical granule p of row r holds global cols ((p ^ (r&7))*8 .. +8)
// -> conflict-free b128 fragment reads, coalesced swizzled staging.
// ---------------------------------------------------------------------------
#define BM 128
#define BN 128
#define BK 64

__global__ __launch_bounds__(256, 2)
void gemm_bt(const unsigned short* __restrict__ A,
             const unsigned short* __restrict__ Wt,
             const float* __restrict__ bias,
             float* __restrict__ Cf,
             unsigned short* __restrict__ Cb,
             int K, int ldc, int relu)
{
    __shared__ __attribute__((aligned(16))) unsigned short As[2][BM * BK];
    __shared__ __attribute__((aligned(16))) unsigned short Bs[2][BN * BK];

    const int tid  = threadIdx.x;
    const int lane = tid & 63;
    const int wave = tid >> 6;
    const int bm = blockIdx.y * BM;
    const int bn = blockIdx.x * BN;
    const int wm = (wave >> 1) * 64;
    const int wn = (wave & 1) * 64;

    // staging: wave w covers rows [32w,32w+32); 4 issues x (8 rows x 128B)
    const int srow = lane >> 3;                 // 0..7
    const int scol = ((lane & 7) ^ srow) * 8;   // XOR-swizzled source col
    const unsigned short* Ag = A  + (size_t)(bm + wave * 32 + srow) * K + scol;
    const unsigned short* Wg = Wt + (size_t)(bn + wave * 32 + srow) * K + scol;
    const size_t istep = (size_t)8 * K;         // +8 rows per issue
    const int lbase = wave * 2048;              // elems (wave*256 granules *8)

    const int fm  = lane & 15;
    const int g4  = lane >> 4;                  // logical granule within k-step
    const int fsw = fm & 7;                     // fragment row & 7

    floatx4 acc[4][4] = {};
    const int iters = K >> 6;

    // prologue: stage buf 0
    #pragma unroll
    for (int t = 0; t < 4; t++) {
        gld16(Ag + t * istep, &As[0][lbase + t * 512]);
        gld16(Wg + t * istep, &Bs[0][lbase + t * 512]);
    }

    for (int i = 0; i < iters; i++) {
        const int cur = i & 1;
        __syncthreads();   // vmcnt(0) drain: buf[cur] resident; old reads done
        if (i + 1 < iters) {
            const int nxt = cur ^ 1;
            const unsigned short* Agn = Ag + (size_t)(i + 1) * BK;
            const unsigned short* Wgn = Wg + (size_t)(i + 1) * BK;
            #pragma unroll
            for (int t = 0; t < 4; t++) {
                gld16(Agn + t * istep, &As[nxt][lbase + t * 512]);
                gld16(Wgn + t * istep, &Bs[nxt][lbase + t * 512]);
            }
        }
        #pragma unroll
        for (int s = 0; s < 2; s++) {
            const int pg = ((s * 4 + g4) ^ fsw) * 8;   // physical granule *8
            bf16x8 af[4], bf[4];
            #pragma unroll
            for (int ii = 0; ii < 4; ii++)
                af[ii] = *(const bf16x8*)(&As[cur][(wm + ii * 16 + fm) * BK + pg]);
            #pragma unroll
            for (int j = 0; j < 4; j++)
                bf[j] = *(const bf16x8*)(&Bs[cur][(wn + j * 16 + fm) * BK + pg]);
            #pragma unroll
            for (int ii = 0; ii < 4; ii++)
                #pragma unroll
                for (int j = 0; j < 4; j++)
                    acc[ii][j] = __builtin_amdgcn_mfma_f32_16x16x32_bf16(
                        af[ii], bf[j], acc[ii][j], 0, 0, 0);
        }
    }

    const int r0 = bm + wm + (lane >> 4) * 4;
    const int c0e = bn + wn + (lane & 15);
    #pragma unroll
    for (int i = 0; i < 4; i++) {
        #pragma unroll
        for (int j = 0; j < 4; j++) {
            const int col = c0e + j * 16;
            const float bv = bias[col];
            #pragma unroll
            for (int r = 0; r < 4; r++) {
                const int row = r0 + i * 16 + r;
                float v = acc[i][j][r] + bv;
                if (relu) v = fmaxf(v, 0.0f);
                if (Cf) Cf[(size_t)row * ldc + col] = v;
                if (Cb) Cb[(size_t)row * ldc + col] = f2bf(v);
            }
        }
    }
}

// ---------------------------------------------------------------------------
// Banded MFMA windowed attention (unchanged from R2).
// ---------------------------------------------------------------------------
__global__ __launch_bounds__(256, 2)
void attn_mfma(const unsigned short* __restrict__ qkv,   // (B*S) x 3072 bf16
               const float* __restrict__ rel,            // 11 x 64 fp32
               unsigned short* __restrict__ attnb)       // (B*S) x 1024 bf16
{
    __shared__ __attribute__((aligned(16))) unsigned short Qs[64 * 72];
    __shared__ __attribute__((aligned(16))) unsigned short Ks[128 * 72];
    __shared__ __attribute__((aligned(16))) unsigned short Vt[64 * 168];
    __shared__ __attribute__((aligned(16))) unsigned short Rs[16 * 72];
    __shared__ __attribute__((aligned(16))) unsigned short Pl[4 * 16 * 104];
    __shared__ float Qrl[4 * 16 * 12];

    const int t   = threadIdx.x;
    const int blk = blockIdx.x;          // ((b*16 + h)*32 + st)
    const int st  = blk & 31;
    const int h   = (blk >> 5) & 15;
    const int b   = blk >> 9;
    const int s0  = st << 6;
    const int brow0 = b * SEQ;

    const int trow = t >> 3;             // 0..31
    const int tc   = (t & 7) * 8;        // 0,8,..,56
    const uint4 z4 = make_uint4(0, 0, 0, 0);

    #pragma unroll
    for (int p = 0; p < 2; p++) {        // Q: 64 x 64
        int r = trow + p * 32;
        uint4 v = *(const uint4*)(qkv + (size_t)(brow0 + s0 + r) * 3072 + h * 64 + tc);
        *(uint4*)(Qs + r * 72 + tc) = v;
    }
    #pragma unroll
    for (int p = 0; p < 4; p++) {        // K + V(transposed): 128 band rows
        int kr = trow + p * 32;
        int ka = s0 - 25 + kr;
        bool in = (ka >= 0) & (ka < SEQ);
        uint4 kv = z4, vv = z4;
        if (in) {
            kv = *(const uint4*)(qkv + (size_t)(brow0 + ka) * 3072 + 1024 + h * 64 + tc);
            vv = *(const uint4*)(qkv + (size_t)(brow0 + ka) * 3072 + 2048 + h * 64 + tc);
        }
        *(uint4*)(Ks + kr * 72 + tc) = kv;
        const unsigned short* e = (const unsigned short*)&vv;
        #pragma unroll
        for (int j = 0; j < 8; j++)
            Vt[(tc + j) * 168 + kr] = e[j];
    }
    if (t < 176) {
        float4 f = ((const float4*)rel)[t];
        int fi = t * 4, rr = fi >> 6, cc = fi & 63;
        ushort4 u;
        u.x = f2bf(f.x); u.y = f2bf(f.y); u.z = f2bf(f.z); u.w = f2bf(f.w);
        *(ushort4*)(Rs + rr * 72 + cc) = u;
    } else {
        int fi = 704 + (t - 176) * 4, rr = fi >> 6, cc = fi & 63;
        *(ushort4*)(Rs + rr * 72 + cc) = make_ushort4(0, 0, 0, 0);
    }
    {
        int n = t * 4, w2 = n >> 8, rem = n & 255, rr = rem >> 4, cc = 80 + (rem & 15);
        *(ushort4*)(Pl + w2 * (16 * 104) + rr * 104 + cc) = make_ushort4(0, 0, 0, 0);
    }
    for (int idx = t; idx < 320; idx += 256) {
        int r = idx / 5, cchunk = idx % 5;
        *(uint4*)(Vt + r * 168 + 128 + cchunk * 8) = z4;
    }
    __syncthreads();

    const int wave = t >> 6;
    const int lane = t & 63;
    const int fm   = lane & 15;
    const int fk8  = (lane >> 4) * 8;
    const int S0w  = s0 + wave * 16;
    unsigned short* Plw = Pl + wave * (16 * 104);
    float* Ql = Qrl + wave * (16 * 12);

    bf16x8 qa0 = *(const bf16x8*)(Qs + (wave * 16 + fm) * 72 + fk8);
    bf16x8 qa1 = *(const bf16x8*)(Qs + (wave * 16 + fm) * 72 + fk8 + 32);

    floatx4 Sc[5];
    #pragma unroll
    for (int nt = 0; nt < 5; nt++) {
        bf16x8 kb0 = *(const bf16x8*)(Ks + (wave * 16 + nt * 16 + fm) * 72 + fk8);
        bf16x8 kb1 = *(const bf16x8*)(Ks + (wave * 16 + nt * 16 + fm) * 72 + fk8 + 32);
        floatx4 acc = {0.f, 0.f, 0.f, 0.f};
        acc = __builtin_amdgcn_mfma_f32_16x16x32_bf16(qa0, kb0, acc, 0, 0, 0);
        acc = __builtin_amdgcn_mfma_f32_16x16x32_bf16(qa1, kb1, acc, 0, 0, 0);
        Sc[nt] = acc;
    }
    {
        bf16x8 rb0 = *(const bf16x8*)(Rs + fm * 72 + fk8);
        bf16x8 rb1 = *(const bf16x8*)(Rs + fm * 72 + fk8 + 32);
        floatx4 qr = {0.f, 0.f, 0.f, 0.f};
        qr = __builtin_amdgcn_mfma_f32_16x16x32_bf16(qa0, rb0, qr, 0, 0, 0);
        qr = __builtin_amdgcn_mfma_f32_16x16x32_bf16(qa1, rb1, qr, 0, 0, 0);
        if (fm < 12) {
            #pragma unroll
            for (int reg = 0; reg < 4; reg++)
                Ql[((lane >> 4) * 4 + reg) * 12 + fm] = qr[reg];
        }
    }

    float inv[4];
    const int iq0 = (lane >> 4) * 4;
    #pragma unroll
    for (int reg = 0; reg < 4; reg++) {
        const int i = iq0 + reg;
        float sc[5];
        float mx = -1e30f;
        #pragma unroll
        for (int nt = 0; nt < 5; nt++) {
            int c   = nt * 16 + fm;
            int off = c - 25 - i;
            int ka  = S0w - 25 + c;
            bool valid = (off >= -RAD) & (off <= RAD) & (ka >= 0) & (ka < SEQ);
            int rid = min(max(off, -5), 5) + 5;
            float v = valid ? (Sc[nt][reg] + Ql[i * 12 + rid]) * 0.125f : -1e30f;
            sc[nt] = v;
            mx = fmaxf(mx, v);
        }
        #pragma unroll
        for (int o = 1; o < 16; o <<= 1) mx = fmaxf(mx, __shfl_xor(mx, o));
        float sum = 0.f;
        #pragma unroll
        for (int nt = 0; nt < 5; nt++) {
            float e = __expf(sc[nt] - mx);
            sum += e;
            Plw[i * 104 + nt * 16 + fm] = f2bf(e);
        }
        #pragma unroll
        for (int o = 1; o < 16; o <<= 1) sum += __shfl_xor(sum, o);
        inv[reg] = 1.0f / sum;
    }

    floatx4 O[4] = {};
    #pragma unroll
    for (int kc = 0; kc < 3; kc++) {
        bf16x8 pa = *(const bf16x8*)(Plw + fm * 104 + fk8 + kc * 32);
        #pragma unroll
        for (int nt = 0; nt < 4; nt++) {
            bf16x8 vb = *(const bf16x8*)(Vt + (nt * 16 + fm) * 168 + wave * 16 + fk8 + kc * 32);
            O[nt] = __builtin_amdgcn_mfma_f32_16x16x32_bf16(pa, vb, O[nt], 0, 0, 0);
        }
    }

    #pragma unroll
    for (int nt = 0; nt < 4; nt++) {
        const int d = nt * 16 + fm;
        #pragma unroll
        for (int reg = 0; reg < 4; reg++) {
            const int i = iq0 + reg;
            attnb[(size_t)(brow0 + S0w + i) * 1024 + h * 64 + d] = f2bf(O[nt][reg] * inv[reg]);
        }
    }
}

// ---------------------------------------------------------------------------
// Fused residual + LayerNorm (unchanged)
// ---------------------------------------------------------------------------
__global__ __launch_bounds__(256)
void ln_fuse(const float* __restrict__ af,
             const unsigned short* __restrict__ ab,
             const float* __restrict__ bres,
             const float* __restrict__ gamma,
             const float* __restrict__ beta,
             float* __restrict__ outf,
             unsigned short* __restrict__ outb)
{
    const int wave = threadIdx.x >> 6;
    const int lane = threadIdx.x & 63;
    const int row = blockIdx.x * 4 + wave;
    const size_t base = (size_t)row * D_MODEL;

    float x[16];
    float sum = 0.0f, sq = 0.0f;
    #pragma unroll
    for (int i = 0; i < 4; i++) {
        const int c4 = lane + i * 64;
        float4 vb = ((const float4*)(bres + base))[c4];
        float4 va;
        if (af) {
            va = ((const float4*)(af + base))[c4];
        } else {
            ushort4 ua = ((const ushort4*)(ab + base))[c4];
            va.x = bf2f(ua.x); va.y = bf2f(ua.y); va.z = bf2f(ua.z); va.w = bf2f(ua.w);
        }
        float e0 = va.x + vb.x, e1 = va.y + vb.y, e2 = va.z + vb.z, e3 = va.w + vb.w;
        x[i*4+0] = e0; x[i*4+1] = e1; x[i*4+2] = e2; x[i*4+3] = e3;
        sum += e0 + e1 + e2 + e3;
        sq  += e0*e0 + e1*e1 + e2*e2 + e3*e3;
    }
    #pragma unroll
    for (int off = 32; off > 0; off >>= 1) {
        sum += __shfl_xor(sum, off);
        sq  += __shfl_xor(sq,  off);
    }
    const float mean = sum * (1.0f / 1024.0f);
    const float var  = sq  * (1.0f / 1024.0f) - mean * mean;
    const float rs   = rsqrtf(var + 1e-5f);

    #pragma unroll
    for (int i = 0; i < 4; i++) {
        const int c4 = lane + i * 64;
        float4 g4 = ((const float4*)gamma)[c4];
        float4 b4 = ((const float4*)beta)[c4];
        float4 o;
        o.x = (x[i*4+0] - mean) * rs * g4.x + b4.x;
        o.y = (x[i*4+1] - mean) * rs * g4.y + b4.y;
        o.z = (x[i*4+2] - mean) * rs * g4.z + b4.z;
        o.w = (x[i*4+3] - mean) * rs * g4.w + b4.w;
        if (outf) ((float4*)(outf + base))[c4] = o;
        if (outb) {
            ushort4 u;
            u.x = f2bf(o.x); u.y = f2bf(o.y); u.z = f2bf(o.z); u.w = f2bf(o.w);
            ((ushort4*)(outb + base))[c4] = u;
        }
    }
}

// ---------------------------------------------------------------------------
extern "C" void kernel_launch(void* const* d_in, const int* in_sizes, int n_in,
                              void* d_out, int out_size, void* d_ws, size_t ws_size,
                              hipStream_t stream)
{
    const float* src = (const float*)d_in[0];
    const float* wq  = (const float*)d_in[1];
    const float* bq  = (const float*)d_in[2];
    const float* wk  = (const float*)d_in[3];
    const float* bk  = (const float*)d_in[4];
    const float* wv  = (const float*)d_in[5];
    const float* bv  = (const float*)d_in[6];
    const float* wo  = (const float*)d_in[7];
    const float* bo  = (const float*)d_in[8];
    const float* rel = (const float*)d_in[9];
    const float* w1  = (const float*)d_in[10];
    const float* b1  = (const float*)d_in[11];
    const float* w2  = (const float*)d_in[12];
    const float* b2  = (const float*)d_in[13];
    const float* g1  = (const float*)d_in[14];
    const float* be1 = (const float*)d_in[15];
    const float* g2  = (const float*)d_in[16];
    const float* be2 = (const float*)d_in[17];
    float* out = (float*)d_out;

    char* ws = (char*)d_ws;
    const size_t MB = 1048576;
    unsigned short* wqkvb = (unsigned short*)(ws + 0);        //  6 MB
    unsigned short* wob   = (unsigned short*)(ws + 6  * MB);  //  2 MB
    unsigned short* w1b   = (unsigned short*)(ws + 8  * MB);  //  8 MB
    unsigned short* w2b   = (unsigned short*)(ws + 16 * MB);  //  8 MB
    float*          bqkv  = (float*)         (ws + 24 * MB);  // 12 KB
    unsigned short* xb    = (unsigned short*)(ws + 25 * MB);  //  8 MB (dead after QKV)
    unsigned short* attnb = (unsigned short*)(ws + 25 * MB);  //  reuse xb
    unsigned short* qkvb  = (unsigned short*)(ws + 33 * MB);  // 24 MB (dead after attn)
    unsigned short* ff1b  = (unsigned short*)(ws + 33 * MB);  // 32 MB, reuse
    float*          z     = (float*)         (ws + 65 * MB);  // 16 MB (dead after LN1)
    float*          ff2   = (float*)         (ws + 65 * MB);  //  reuse z
    unsigned short* x1b   = (unsigned short*)(ws + 81 * MB);  //  8 MB

    cvt4<<<4096, 256, 0, stream>>>(src, xb, 1048576);
    cvt4<<<1024, 256, 0, stream>>>(wq, wqkvb,           262144);
    cvt4<<<1024, 256, 0, stream>>>(wk, wqkvb + 1048576, 262144);
    cvt4<<<1024, 256, 0, stream>>>(wv, wqkvb + 2097152, 262144);
    cvt4<<<1024, 256, 0, stream>>>(wo, wob, 262144);
    cvt4<<<4096, 256, 0, stream>>>(w1, w1b, 1048576);
    cvt4<<<4096, 256, 0, stream>>>(w2, w2b, 1048576);
    concat3<<<12, 256, 0, stream>>>(bq, bk, bv, bqkv);

    const dim3 blk(256);
    gemm_bt<<<dim3(3072 / BN, NROWS / BM), blk, 0, stream>>>(
        xb, wqkvb, bqkv, nullptr, qkvb, 1024, 3072, 0);
    attn_mfma<<<1024, blk, 0, stream>>>(qkvb, rel, attnb);
    gemm_bt<<<dim3(1024 / BN, NROWS / BM), blk, 0, stream>>>(
        attnb, wob, bo, z, nullptr, 1024, 1024, 0);
    ln_fuse<<<NROWS / 4, blk, 0, stream>>>(src, nullptr, z, g1, be1, nullptr, x1b);
    gemm_bt<<<dim3(4096 / BN, NROWS / BM), blk, 0, stream>>>(
        x1b, w1b, b1, nullptr, ff1b, 1024, 4096, 1);
    gemm_bt<<<dim3(1024 / BN, NROWS / BM), blk, 0, stream>>>(
        ff1b, w2b, b2, ff2, nullptr, 4096, 1024, 0);
    ln_fuse<<<NROWS / 4, blk, 0, stream>>>(nullptr, x1b, ff2, g2, be2, out, nullptr);
}

// Round 5
// 321.950 us; speedup vs baseline: 1.1424x; 1.1043x over previous
//
#include <hip/hip_runtime.h>

// ============================================================================
// ETC layer: windowed rel-pos attention + FFN, bf16 MFMA GEMMs on gfx950
//   B=2 S=2048 D_MODEL=1024 NHEAD=16 DHEAD=64 DFF=4096 R=25 W=51 K=5
// R5: XCD-aware tile swizzle in gemm_bt (L2 locality; id%8 = XCD);
//     split-K=2 for WO/FF2 (bf16 partials, reduced+biased inside ln_fuse).
// ============================================================================

#define D_MODEL 1024
#define SEQ     2048
#define NROWS   4096      // B*S
#define WIN     51
#define RAD     25

typedef __attribute__((ext_vector_type(8))) __bf16 bf16x8;
typedef __attribute__((ext_vector_type(4))) float  floatx4;

__device__ __forceinline__ unsigned short f2bf(float x) {
    unsigned u = __float_as_uint(x);
    unsigned r = u + 0x7fffu + ((u >> 16) & 1u);
    return (unsigned short)(r >> 16);
}
__device__ __forceinline__ float bf2f(unsigned short h) {
    return __uint_as_float(((unsigned)h) << 16);
}

// async global->LDS 16B per lane; LDS dest = wave-uniform base + lane*16
__device__ __forceinline__ void gld16(const unsigned short* g, unsigned short* l) {
    __builtin_amdgcn_global_load_lds(
        (const __attribute__((address_space(1))) unsigned int*)g,
        (__attribute__((address_space(3))) unsigned int*)l,
        16, 0, 0);
}

// ---------------------------------------------------------------------------
__global__ __launch_bounds__(256) void cvt4(const float* __restrict__ in,
                                            unsigned short* __restrict__ out,
                                            int n4) {
    int i = blockIdx.x * 256 + threadIdx.x;
    if (i >= n4) return;
    float4 f = ((const float4*)in)[i];
    ushort4 u;
    u.x = f2bf(f.x); u.y = f2bf(f.y); u.z = f2bf(f.z); u.w = f2bf(f.w);
    ((ushort4*)out)[i] = u;
}

__global__ __launch_bounds__(256) void concat3(const float* __restrict__ a,
                                               const float* __restrict__ b,
                                               const float* __restrict__ c,
                                               float* __restrict__ out) {
    int i = blockIdx.x * 256 + threadIdx.x;   // 3072 total
    if (i >= 3072) return;
    float v = (i < 1024) ? a[i] : (i < 2048 ? b[i - 1024] : c[i - 2048]);
    out[i] = v;
}

// ---------------------------------------------------------------------------
// GEMM  C[M,N] = A[M,K] @ W[N,K]^T (+bias,relu)   (bf16 in, fp32 acc)
// 128x128 tile, 4 waves, 16x16x32 MFMA, BK=64, dbuf LDS, XOR-swizzled
// granules (R4). New in R5:
//  - grid is 1D: blockIdx.x = s*T + t  (s = K-slice, T = tiles per slice)
//  - XCD swizzle: t%8 = XCD (dispatch round-robin); per-XCD contiguous sid
//    range mapped column-major over 4x8 tile-rects -> per-XCD L2 locality.
//    Requires M=4096 (gm=32), gn%8==0, T%32==0.
//  - split-K: slice s computes A[:, s*kloop : (s+1)*kloop] @ W^T slice and
//    writes bf16 partials at Cb + s*4096*ldc (no bias/relu when sliced).
// ---------------------------------------------------------------------------
#define BM 128
#define BN 128
#define BK 64

__global__ __launch_bounds__(256, 2)
void gemm_bt(const unsigned short* __restrict__ A,
             const unsigned short* __restrict__ Wt,
             const float* __restrict__ bias,
             unsigned short* __restrict__ Cb,
             int kstride, int kloop, int T, int ldc, int relu)
{
    __shared__ __attribute__((aligned(16))) unsigned short As[2][BM * BK];
    __shared__ __attribute__((aligned(16))) unsigned short Bs[2][BN * BK];

    // ---- slice + XCD-aware tile decode ----
    const int id = blockIdx.x;
    const int s  = id / T;
    const int t  = id - s * T;
    const int sid  = (t & 7) * (T >> 3) + (t >> 3);  // XCD-contiguous
    const int rect = sid >> 5;                       // 4x8 tile rect
    const int r    = sid & 31;
    const int bm = ((rect & 7) * 4 + (r >> 3)) * BM; // rect col-major (gm=32)
    const int bn = ((rect >> 3) * 8 + (r & 7)) * BN;

    const int tid  = threadIdx.x;
    const int lane = tid & 63;
    const int wave = tid >> 6;
    const int wm = (wave >> 1) * 64;
    const int wn = (wave & 1) * 64;

    // staging: wave w covers rows [32w,32w+32); 4 issues x (8 rows x 128B)
    const int srow = lane >> 3;                 // 0..7
    const int scol = ((lane & 7) ^ srow) * 8;   // XOR-swizzled source col
    const int kofs = s * kloop;
    const unsigned short* Ag = A  + (size_t)(bm + wave * 32 + srow) * kstride + kofs + scol;
    const unsigned short* Wg = Wt + (size_t)(bn + wave * 32 + srow) * kstride + kofs + scol;
    const size_t istep = (size_t)8 * kstride;   // +8 rows per issue
    const int lbase = wave * 2048;

    const int fm  = lane & 15;
    const int g4  = lane >> 4;
    const int fsw = fm & 7;

    floatx4 acc[4][4] = {};
    const int iters = kloop >> 6;

    #pragma unroll
    for (int u = 0; u < 4; u++) {
        gld16(Ag + u * istep, &As[0][lbase + u * 512]);
        gld16(Wg + u * istep, &Bs[0][lbase + u * 512]);
    }

    for (int i = 0; i < iters; i++) {
        const int cur = i & 1;
        __syncthreads();   // vmcnt(0) drain: buf[cur] resident; old reads done
        if (i + 1 < iters) {
            const int nxt = cur ^ 1;
            const unsigned short* Agn = Ag + (size_t)(i + 1) * BK;
            const unsigned short* Wgn = Wg + (size_t)(i + 1) * BK;
            #pragma unroll
            for (int u = 0; u < 4; u++) {
                gld16(Agn + u * istep, &As[nxt][lbase + u * 512]);
                gld16(Wgn + u * istep, &Bs[nxt][lbase + u * 512]);
            }
        }
        #pragma unroll
        for (int sh = 0; sh < 2; sh++) {
            const int pg = ((sh * 4 + g4) ^ fsw) * 8;
            bf16x8 af[4], bf[4];
            #pragma unroll
            for (int ii = 0; ii < 4; ii++)
                af[ii] = *(const bf16x8*)(&As[cur][(wm + ii * 16 + fm) * BK + pg]);
            #pragma unroll
            for (int j = 0; j < 4; j++)
                bf[j] = *(const bf16x8*)(&Bs[cur][(wn + j * 16 + fm) * BK + pg]);
            #pragma unroll
            for (int ii = 0; ii < 4; ii++)
                #pragma unroll
                for (int j = 0; j < 4; j++)
                    acc[ii][j] = __builtin_amdgcn_mfma_f32_16x16x32_bf16(
                        af[ii], bf[j], acc[ii][j], 0, 0, 0);
        }
    }

    unsigned short* Co = Cb + (size_t)s * NROWS * ldc;
    const int r0 = bm + wm + (lane >> 4) * 4;
    const int c0e = bn + wn + (lane & 15);
    #pragma unroll
    for (int i = 0; i < 4; i++) {
        #pragma unroll
        for (int j = 0; j < 4; j++) {
            const int col = c0e + j * 16;
            const float bv = bias ? bias[col] : 0.0f;
            #pragma unroll
            for (int rr = 0; rr < 4; rr++) {
                const int row = r0 + i * 16 + rr;
                float v = acc[i][j][rr] + bv;
                if (relu) v = fmaxf(v, 0.0f);
                Co[(size_t)row * ldc + col] = f2bf(v);
            }
        }
    }
}

// ---------------------------------------------------------------------------
// Banded MFMA windowed attention (unchanged from R2).
// ---------------------------------------------------------------------------
__global__ __launch_bounds__(256, 2)
void attn_mfma(const unsigned short* __restrict__ qkv,   // (B*S) x 3072 bf16
               const float* __restrict__ rel,            // 11 x 64 fp32
               unsigned short* __restrict__ attnb)       // (B*S) x 1024 bf16
{
    __shared__ __attribute__((aligned(16))) unsigned short Qs[64 * 72];
    __shared__ __attribute__((aligned(16))) unsigned short Ks[128 * 72];
    __shared__ __attribute__((aligned(16))) unsigned short Vt[64 * 168];
    __shared__ __attribute__((aligned(16))) unsigned short Rs[16 * 72];
    __shared__ __attribute__((aligned(16))) unsigned short Pl[4 * 16 * 104];
    __shared__ float Qrl[4 * 16 * 12];

    const int t   = threadIdx.x;
    const int blk = blockIdx.x;          // ((b*16 + h)*32 + st)
    const int st  = blk & 31;
    const int h   = (blk >> 5) & 15;
    const int b   = blk >> 9;
    const int s0  = st << 6;
    const int brow0 = b * SEQ;

    const int trow = t >> 3;             // 0..31
    const int tc   = (t & 7) * 8;        // 0,8,..,56
    const uint4 z4 = make_uint4(0, 0, 0, 0);

    #pragma unroll
    for (int p = 0; p < 2; p++) {        // Q: 64 x 64
        int r = trow + p * 32;
        uint4 v = *(const uint4*)(qkv + (size_t)(brow0 + s0 + r) * 3072 + h * 64 + tc);
        *(uint4*)(Qs + r * 72 + tc) = v;
    }
    #pragma unroll
    for (int p = 0; p < 4; p++) {        // K + V(transposed): 128 band rows
        int kr = trow + p * 32;
        int ka = s0 - 25 + kr;
        bool in = (ka >= 0) & (ka < SEQ);
        uint4 kv = z4, vv = z4;
        if (in) {
            kv = *(const uint4*)(qkv + (size_t)(brow0 + ka) * 3072 + 1024 + h * 64 + tc);
            vv = *(const uint4*)(qkv + (size_t)(brow0 + ka) * 3072 + 2048 + h * 64 + tc);
        }
        *(uint4*)(Ks + kr * 72 + tc) = kv;
        const unsigned short* e = (const unsigned short*)&vv;
        #pragma unroll
        for (int j = 0; j < 8; j++)
            Vt[(tc + j) * 168 + kr] = e[j];
    }
    if (t < 176) {
        float4 f = ((const float4*)rel)[t];
        int fi = t * 4, rr = fi >> 6, cc = fi & 63;
        ushort4 u;
        u.x = f2bf(f.x); u.y = f2bf(f.y); u.z = f2bf(f.z); u.w = f2bf(f.w);
        *(ushort4*)(Rs + rr * 72 + cc) = u;
    } else {
        int fi = 704 + (t - 176) * 4, rr = fi >> 6, cc = fi & 63;
        *(ushort4*)(Rs + rr * 72 + cc) = make_ushort4(0, 0, 0, 0);
    }
    {
        int n = t * 4, w2 = n >> 8, rem = n & 255, rr = rem >> 4, cc = 80 + (rem & 15);
        *(ushort4*)(Pl + w2 * (16 * 104) + rr * 104 + cc) = make_ushort4(0, 0, 0, 0);
    }
    for (int idx = t; idx < 320; idx += 256) {
        int r = idx / 5, cchunk = idx % 5;
        *(uint4*)(Vt + r * 168 + 128 + cchunk * 8) = z4;
    }
    __syncthreads();

    const int wave = t >> 6;
    const int lane = t & 63;
    const int fm   = lane & 15;
    const int fk8  = (lane >> 4) * 8;
    const int S0w  = s0 + wave * 16;
    unsigned short* Plw = Pl + wave * (16 * 104);
    float* Ql = Qrl + wave * (16 * 12);

    bf16x8 qa0 = *(const bf16x8*)(Qs + (wave * 16 + fm) * 72 + fk8);
    bf16x8 qa1 = *(const bf16x8*)(Qs + (wave * 16 + fm) * 72 + fk8 + 32);

    floatx4 Sc[5];
    #pragma unroll
    for (int nt = 0; nt < 5; nt++) {
        bf16x8 kb0 = *(const bf16x8*)(Ks + (wave * 16 + nt * 16 + fm) * 72 + fk8);
        bf16x8 kb1 = *(const bf16x8*)(Ks + (wave * 16 + nt * 16 + fm) * 72 + fk8 + 32);
        floatx4 acc = {0.f, 0.f, 0.f, 0.f};
        acc = __builtin_amdgcn_mfma_f32_16x16x32_bf16(qa0, kb0, acc, 0, 0, 0);
        acc = __builtin_amdgcn_mfma_f32_16x16x32_bf16(qa1, kb1, acc, 0, 0, 0);
        Sc[nt] = acc;
    }
    {
        bf16x8 rb0 = *(const bf16x8*)(Rs + fm * 72 + fk8);
        bf16x8 rb1 = *(const bf16x8*)(Rs + fm * 72 + fk8 + 32);
        floatx4 qr = {0.f, 0.f, 0.f, 0.f};
        qr = __builtin_amdgcn_mfma_f32_16x16x32_bf16(qa0, rb0, qr, 0, 0, 0);
        qr = __builtin_amdgcn_mfma_f32_16x16x32_bf16(qa1, rb1, qr, 0, 0, 0);
        if (fm < 12) {
            #pragma unroll
            for (int reg = 0; reg < 4; reg++)
                Ql[((lane >> 4) * 4 + reg) * 12 + fm] = qr[reg];
        }
    }

    float inv[4];
    const int iq0 = (lane >> 4) * 4;
    #pragma unroll
    for (int reg = 0; reg < 4; reg++) {
        const int i = iq0 + reg;
        float sc[5];
        float mx = -1e30f;
        #pragma unroll
        for (int nt = 0; nt < 5; nt++) {
            int c   = nt * 16 + fm;
            int off = c - 25 - i;
            int ka  = S0w - 25 + c;
            bool valid = (off >= -RAD) & (off <= RAD) & (ka >= 0) & (ka < SEQ);
            int rid = min(max(off, -5), 5) + 5;
            float v = valid ? (Sc[nt][reg] + Ql[i * 12 + rid]) * 0.125f : -1e30f;
            sc[nt] = v;
            mx = fmaxf(mx, v);
        }
        #pragma unroll
        for (int o = 1; o < 16; o <<= 1) mx = fmaxf(mx, __shfl_xor(mx, o));
        float sum = 0.f;
        #pragma unroll
        for (int nt = 0; nt < 5; nt++) {
            float e = __expf(sc[nt] - mx);
            sum += e;
            Plw[i * 104 + nt * 16 + fm] = f2bf(e);
        }
        #pragma unroll
        for (int o = 1; o < 16; o <<= 1) sum += __shfl_xor(sum, o);
        inv[reg] = 1.0f / sum;
    }

    floatx4 O[4] = {};
    #pragma unroll
    for (int kc = 0; kc < 3; kc++) {
        bf16x8 pa = *(const bf16x8*)(Plw + fm * 104 + fk8 + kc * 32);
        #pragma unroll
        for (int nt = 0; nt < 4; nt++) {
            bf16x8 vb = *(const bf16x8*)(Vt + (nt * 16 + fm) * 168 + wave * 16 + fk8 + kc * 32);
            O[nt] = __builtin_amdgcn_mfma_f32_16x16x32_bf16(pa, vb, O[nt], 0, 0, 0);
        }
    }

    #pragma unroll
    for (int nt = 0; nt < 4; nt++) {
        const int d = nt * 16 + fm;
        #pragma unroll
        for (int reg = 0; reg < 4; reg++) {
            const int i = iq0 + reg;
            attnb[(size_t)(brow0 + S0w + i) * 1024 + h * 64 + d] = f2bf(O[nt][reg] * inv[reg]);
        }
    }
}

// ---------------------------------------------------------------------------
// Fused (residual + bf16 K-slice partials + column bias) + LayerNorm.
// x = res + p0 + p1 + cbias;  out = LN(x)*g+b.  One wave per 1024-col row.
// ---------------------------------------------------------------------------
__global__ __launch_bounds__(256)
void ln_fuse(const float* __restrict__ resf,
             const unsigned short* __restrict__ resb,
             const unsigned short* __restrict__ p0,
             const unsigned short* __restrict__ p1,
             const float* __restrict__ cbias,
             const float* __restrict__ gamma,
             const float* __restrict__ beta,
             float* __restrict__ outf,
             unsigned short* __restrict__ outb)
{
    const int wave = threadIdx.x >> 6;
    const int lane = threadIdx.x & 63;
    const int row = blockIdx.x * 4 + wave;
    const size_t base = (size_t)row * D_MODEL;

    float x[16];
    float sum = 0.0f, sq = 0.0f;
    #pragma unroll
    for (int i = 0; i < 4; i++) {
        const int c4 = lane + i * 64;
        ushort4 u0 = ((const ushort4*)(p0 + base))[c4];
        ushort4 u1 = ((const ushort4*)(p1 + base))[c4];
        float4 cb = ((const float4*)cbias)[c4];
        float4 va;
        if (resf) {
            va = ((const float4*)(resf + base))[c4];
        } else {
            ushort4 ua = ((const ushort4*)(resb + base))[c4];
            va.x = bf2f(ua.x); va.y = bf2f(ua.y); va.z = bf2f(ua.z); va.w = bf2f(ua.w);
        }
        float e0 = va.x + bf2f(u0.x) + bf2f(u1.x) + cb.x;
        float e1 = va.y + bf2f(u0.y) + bf2f(u1.y) + cb.y;
        float e2 = va.z + bf2f(u0.z) + bf2f(u1.z) + cb.z;
        float e3 = va.w + bf2f(u0.w) + bf2f(u1.w) + cb.w;
        x[i*4+0] = e0; x[i*4+1] = e1; x[i*4+2] = e2; x[i*4+3] = e3;
        sum += e0 + e1 + e2 + e3;
        sq  += e0*e0 + e1*e1 + e2*e2 + e3*e3;
    }
    #pragma unroll
    for (int off = 32; off > 0; off >>= 1) {
        sum += __shfl_xor(sum, off);
        sq  += __shfl_xor(sq,  off);
    }
    const float mean = sum * (1.0f / 1024.0f);
    const float var  = sq  * (1.0f / 1024.0f) - mean * mean;
    const float rs   = rsqrtf(var + 1e-5f);

    #pragma unroll
    for (int i = 0; i < 4; i++) {
        const int c4 = lane + i * 64;
        float4 g4 = ((const float4*)gamma)[c4];
        float4 b4 = ((const float4*)beta)[c4];
        float4 o;
        o.x = (x[i*4+0] - mean) * rs * g4.x + b4.x;
        o.y = (x[i*4+1] - mean) * rs * g4.y + b4.y;
        o.z = (x[i*4+2] - mean) * rs * g4.z + b4.z;
        o.w = (x[i*4+3] - mean) * rs * g4.w + b4.w;
        if (outf) ((float4*)(outf + base))[c4] = o;
        if (outb) {
            ushort4 u;
            u.x = f2bf(o.x); u.y = f2bf(o.y); u.z = f2bf(o.z); u.w = f2bf(o.w);
            ((ushort4*)(outb + base))[c4] = u;
        }
    }
}

// ---------------------------------------------------------------------------
extern "C" void kernel_launch(void* const* d_in, const int* in_sizes, int n_in,
                              void* d_out, int out_size, void* d_ws, size_t ws_size,
                              hipStream_t stream)
{
    const float* src = (const float*)d_in[0];
    const float* wq  = (const float*)d_in[1];
    const float* bq  = (const float*)d_in[2];
    const float* wk  = (const float*)d_in[3];
    const float* bk  = (const float*)d_in[4];
    const float* wv  = (const float*)d_in[5];
    const float* bv  = (const float*)d_in[6];
    const float* wo  = (const float*)d_in[7];
    const float* bo  = (const float*)d_in[8];
    const float* rel = (const float*)d_in[9];
    const float* w1  = (const float*)d_in[10];
    const float* b1  = (const float*)d_in[11];
    const float* w2  = (const float*)d_in[12];
    const float* b2  = (const float*)d_in[13];
    const float* g1  = (const float*)d_in[14];
    const float* be1 = (const float*)d_in[15];
    const float* g2  = (const float*)d_in[16];
    const float* be2 = (const float*)d_in[17];
    float* out = (float*)d_out;

    char* ws = (char*)d_ws;
    const size_t MB = 1048576;
    // liveness-based layout (max 89 MB):
    unsigned short* wqkvb = (unsigned short*)(ws + 0);        //  6 MB
    unsigned short* wob   = (unsigned short*)(ws + 6  * MB);  //  2 MB
    unsigned short* w1b   = (unsigned short*)(ws + 8  * MB);  //  8 MB
    unsigned short* w2b   = (unsigned short*)(ws + 16 * MB);  //  8 MB
    float*          bqkv  = (float*)         (ws + 24 * MB);  // 12 KB
    unsigned short* xb    = (unsigned short*)(ws + 25 * MB);  //  8 MB (dead after QKV)
    unsigned short* attnb = (unsigned short*)(ws + 25 * MB);  //  reuse xb
    unsigned short* qkvb  = (unsigned short*)(ws + 33 * MB);  // 24 MB (dead after attn)
    unsigned short* z01   = (unsigned short*)(ws + 33 * MB);  // 16 MB: WO partials s0,s1
    unsigned short* ff1b  = (unsigned short*)(ws + 33 * MB);  // 32 MB (after LN1)
    unsigned short* f01   = (unsigned short*)(ws + 65 * MB);  // 16 MB: FF2 partials s0,s1
    unsigned short* x1b   = (unsigned short*)(ws + 81 * MB);  //  8 MB (ends 89)
    const size_t SL = (size_t)NROWS * 1024;                   // partial slice elems

    cvt4<<<4096, 256, 0, stream>>>(src, xb, 1048576);
    cvt4<<<1024, 256, 0, stream>>>(wq, wqkvb,           262144);
    cvt4<<<1024, 256, 0, stream>>>(wk, wqkvb + 1048576, 262144);
    cvt4<<<1024, 256, 0, stream>>>(wv, wqkvb + 2097152, 262144);
    cvt4<<<1024, 256, 0, stream>>>(wo, wob, 262144);
    cvt4<<<4096, 256, 0, stream>>>(w1, w1b, 1048576);
    cvt4<<<4096, 256, 0, stream>>>(w2, w2b, 1048576);
    concat3<<<12, 256, 0, stream>>>(bq, bk, bv, bqkv);

    const dim3 blk(256);
    // QKV: 4096x3072, K=1024, no split (T=768)
    gemm_bt<<<768, blk, 0, stream>>>(xb, wqkvb, bqkv, qkvb, 1024, 1024, 768, 3072, 0);
    // windowed attention
    attn_mfma<<<1024, blk, 0, stream>>>(qkvb, rel, attnb);
    // WO: 4096x1024, K=1024 split 2 -> bf16 partials z01 (T=256, grid 512)
    gemm_bt<<<512, blk, 0, stream>>>(attnb, wob, nullptr, z01, 1024, 512, 256, 1024, 0);
    // x1 = LN(src + z0 + z1 + bo)
    ln_fuse<<<NROWS / 4, blk, 0, stream>>>(src, nullptr, z01, z01 + SL, bo, g1, be1,
                                           nullptr, x1b);
    // FF1: 4096x4096, K=1024, relu+bias (T=1024)
    gemm_bt<<<1024, blk, 0, stream>>>(x1b, w1b, b1, ff1b, 1024, 1024, 1024, 4096, 1);
    // FF2: 4096x1024, K=4096 split 2 -> bf16 partials f01 (T=256, grid 512)
    gemm_bt<<<512, blk, 0, stream>>>(ff1b, w2b, nullptr, f01, 4096, 2048, 256, 1024, 0);
    // out = LN(x1 + f0 + f1 + b2)
    ln_fuse<<<NROWS / 4, blk, 0, stream>>>(nullptr, x1b, f01, f01 + SL, b2, g2, be2,
                                           out, nullptr);
}

// Round 6
// 314.245 us; speedup vs baseline: 1.1704x; 1.0245x over previous
//
#include <hip/hip_runtime.h>

// ============================================================================
// ETC layer: windowed rel-pos attention + FFN, bf16 MFMA GEMMs on gfx950
//   B=2 S=2048 D_MODEL=1024 NHEAD=16 DHEAD=64 DFF=4096 R=25 W=51 K=5
// R6: all fp32->bf16 conversions + bias concat fused into ONE grid-stride
//     kernel (was 8 launches). GEMM (XCD-swizzled, BK=64 dbuf), attn, LN
//     unchanged from R5.
// ============================================================================

#define D_MODEL 1024
#define SEQ     2048
#define NROWS   4096      // B*S
#define WIN     51
#define RAD     25

typedef __attribute__((ext_vector_type(8))) __bf16 bf16x8;
typedef __attribute__((ext_vector_type(4))) float  floatx4;

__device__ __forceinline__ unsigned short f2bf(float x) {
    unsigned u = __float_as_uint(x);
    unsigned r = u + 0x7fffu + ((u >> 16) & 1u);
    return (unsigned short)(r >> 16);
}
__device__ __forceinline__ float bf2f(unsigned short h) {
    return __uint_as_float(((unsigned)h) << 16);
}

// async global->LDS 16B per lane; LDS dest = wave-uniform base + lane*16
__device__ __forceinline__ void gld16(const unsigned short* g, unsigned short* l) {
    __builtin_amdgcn_global_load_lds(
        (const __attribute__((address_space(1))) unsigned int*)g,
        (__attribute__((address_space(3))) unsigned int*)l,
        16, 0, 0);
}

// ---------------------------------------------------------------------------
// One-shot conversion kernel: src,wq,wk,wv,wo,w1,w2 -> bf16 + bqkv concat.
// Work item = one float4 group. Region decode via cumulative offsets.
//   [0,1048576)          src  -> xb
//   [+262144)            wq   -> wqkvb
//   [+262144)            wk   -> wqkvb+1M elems
//   [+262144)            wv   -> wqkvb+2M elems
//   [+262144)            wo   -> wob
//   [+1048576)           w1   -> w1b
//   [+1048576)           w2   -> w2b
//   [+192)               bq|bk|bv -> bqkv (fp32 copy)
// total 4,194,496 groups
// ---------------------------------------------------------------------------
__device__ __forceinline__ void cvtgrp(const float* __restrict__ in,
                                       unsigned short* __restrict__ out, int g) {
    float4 f = ((const float4*)in)[g];
    ushort4 u;
    u.x = f2bf(f.x); u.y = f2bf(f.y); u.z = f2bf(f.z); u.w = f2bf(f.w);
    ((ushort4*)out)[g] = u;
}

__global__ __launch_bounds__(256)
void cvt_all(const float* __restrict__ src,
             const float* __restrict__ wq, const float* __restrict__ wk,
             const float* __restrict__ wv, const float* __restrict__ wo,
             const float* __restrict__ w1, const float* __restrict__ w2,
             const float* __restrict__ bq, const float* __restrict__ bk,
             const float* __restrict__ bv,
             unsigned short* __restrict__ xb,
             unsigned short* __restrict__ wqkvb,
             unsigned short* __restrict__ wob,
             unsigned short* __restrict__ w1b,
             unsigned short* __restrict__ w2b,
             float* __restrict__ bqkv)
{
    int g = blockIdx.x * 256 + threadIdx.x;
    if (g >= 4194496) return;
    if (g < 1048576) { cvtgrp(src, xb, g); return; }
    g -= 1048576;
    if (g < 262144) { cvtgrp(wq, wqkvb, g); return; }
    g -= 262144;
    if (g < 262144) { cvtgrp(wk, wqkvb + 1048576, g); return; }
    g -= 262144;
    if (g < 262144) { cvtgrp(wv, wqkvb + 2097152, g); return; }
    g -= 262144;
    if (g < 262144) { cvtgrp(wo, wob, g); return; }
    g -= 262144;
    if (g < 1048576) { cvtgrp(w1, w1b, g); return; }
    g -= 1048576;
    if (g < 1048576) { cvtgrp(w2, w2b, g); return; }
    g -= 1048576;
    // biases: 192 fp32 groups
    float4 f = (g < 64) ? ((const float4*)bq)[g]
             : (g < 128) ? ((const float4*)bk)[g - 64]
                         : ((const float4*)bv)[g - 128];
    ((float4*)bqkv)[g] = f;
}

// ---------------------------------------------------------------------------
// GEMM  C[M,N] = A[M,K] @ W[N,K]^T (+bias,relu)   (bf16 in, fp32 acc)
// 128x128 tile, 4 waves, 16x16x32 MFMA, BK=64, dbuf LDS, XOR-swizzled
// granules, XCD-aware tile swizzle, optional split-K (R5 — unchanged).
// ---------------------------------------------------------------------------
#define BM 128
#define BN 128
#define BK 64

__global__ __launch_bounds__(256, 2)
void gemm_bt(const unsigned short* __restrict__ A,
             const unsigned short* __restrict__ Wt,
             const float* __restrict__ bias,
             unsigned short* __restrict__ Cb,
             int kstride, int kloop, int T, int ldc, int relu)
{
    __shared__ __attribute__((aligned(16))) unsigned short As[2][BM * BK];
    __shared__ __attribute__((aligned(16))) unsigned short Bs[2][BN * BK];

    const int id = blockIdx.x;
    const int s  = id / T;
    const int t  = id - s * T;
    const int sid  = (t & 7) * (T >> 3) + (t >> 3);  // XCD-contiguous
    const int rect = sid >> 5;                       // 4x8 tile rect
    const int r    = sid & 31;
    const int bm = ((rect & 7) * 4 + (r >> 3)) * BM;
    const int bn = ((rect >> 3) * 8 + (r & 7)) * BN;

    const int tid  = threadIdx.x;
    const int lane = tid & 63;
    const int wave = tid >> 6;
    const int wm = (wave >> 1) * 64;
    const int wn = (wave & 1) * 64;

    const int srow = lane >> 3;                 // 0..7
    const int scol = ((lane & 7) ^ srow) * 8;   // XOR-swizzled source col
    const int kofs = s * kloop;
    const unsigned short* Ag = A  + (size_t)(bm + wave * 32 + srow) * kstride + kofs + scol;
    const unsigned short* Wg = Wt + (size_t)(bn + wave * 32 + srow) * kstride + kofs + scol;
    const size_t istep = (size_t)8 * kstride;
    const int lbase = wave * 2048;

    const int fm  = lane & 15;
    const int g4  = lane >> 4;
    const int fsw = fm & 7;

    floatx4 acc[4][4] = {};
    const int iters = kloop >> 6;

    #pragma unroll
    for (int u = 0; u < 4; u++) {
        gld16(Ag + u * istep, &As[0][lbase + u * 512]);
        gld16(Wg + u * istep, &Bs[0][lbase + u * 512]);
    }

    for (int i = 0; i < iters; i++) {
        const int cur = i & 1;
        __syncthreads();
        if (i + 1 < iters) {
            const int nxt = cur ^ 1;
            const unsigned short* Agn = Ag + (size_t)(i + 1) * BK;
            const unsigned short* Wgn = Wg + (size_t)(i + 1) * BK;
            #pragma unroll
            for (int u = 0; u < 4; u++) {
                gld16(Agn + u * istep, &As[nxt][lbase + u * 512]);
                gld16(Wgn + u * istep, &Bs[nxt][lbase + u * 512]);
            }
        }
        #pragma unroll
        for (int sh = 0; sh < 2; sh++) {
            const int pg = ((sh * 4 + g4) ^ fsw) * 8;
            bf16x8 af[4], bf[4];
            #pragma unroll
            for (int ii = 0; ii < 4; ii++)
                af[ii] = *(const bf16x8*)(&As[cur][(wm + ii * 16 + fm) * BK + pg]);
            #pragma unroll
            for (int j = 0; j < 4; j++)
                bf[j] = *(const bf16x8*)(&Bs[cur][(wn + j * 16 + fm) * BK + pg]);
            #pragma unroll
            for (int ii = 0; ii < 4; ii++)
                #pragma unroll
                for (int j = 0; j < 4; j++)
                    acc[ii][j] = __builtin_amdgcn_mfma_f32_16x16x32_bf16(
                        af[ii], bf[j], acc[ii][j], 0, 0, 0);
        }
    }

    unsigned short* Co = Cb + (size_t)s * NROWS * ldc;
    const int r0 = bm + wm + (lane >> 4) * 4;
    const int c0e = bn + wn + (lane & 15);
    #pragma unroll
    for (int i = 0; i < 4; i++) {
        #pragma unroll
        for (int j = 0; j < 4; j++) {
            const int col = c0e + j * 16;
            const float bv = bias ? bias[col] : 0.0f;
            #pragma unroll
            for (int rr = 0; rr < 4; rr++) {
                const int row = r0 + i * 16 + rr;
                float v = acc[i][j][rr] + bv;
                if (relu) v = fmaxf(v, 0.0f);
                Co[(size_t)row * ldc + col] = f2bf(v);
            }
        }
    }
}

// ---------------------------------------------------------------------------
// Banded MFMA windowed attention (unchanged from R2).
// ---------------------------------------------------------------------------
__global__ __launch_bounds__(256, 2)
void attn_mfma(const unsigned short* __restrict__ qkv,   // (B*S) x 3072 bf16
               const float* __restrict__ rel,            // 11 x 64 fp32
               unsigned short* __restrict__ attnb)       // (B*S) x 1024 bf16
{
    __shared__ __attribute__((aligned(16))) unsigned short Qs[64 * 72];
    __shared__ __attribute__((aligned(16))) unsigned short Ks[128 * 72];
    __shared__ __attribute__((aligned(16))) unsigned short Vt[64 * 168];
    __shared__ __attribute__((aligned(16))) unsigned short Rs[16 * 72];
    __shared__ __attribute__((aligned(16))) unsigned short Pl[4 * 16 * 104];
    __shared__ float Qrl[4 * 16 * 12];

    const int t   = threadIdx.x;
    const int blk = blockIdx.x;          // ((b*16 + h)*32 + st)
    const int st  = blk & 31;
    const int h   = (blk >> 5) & 15;
    const int b   = blk >> 9;
    const int s0  = st << 6;
    const int brow0 = b * SEQ;

    const int trow = t >> 3;             // 0..31
    const int tc   = (t & 7) * 8;        // 0,8,..,56
    const uint4 z4 = make_uint4(0, 0, 0, 0);

    #pragma unroll
    for (int p = 0; p < 2; p++) {        // Q: 64 x 64
        int r = trow + p * 32;
        uint4 v = *(const uint4*)(qkv + (size_t)(brow0 + s0 + r) * 3072 + h * 64 + tc);
        *(uint4*)(Qs + r * 72 + tc) = v;
    }
    #pragma unroll
    for (int p = 0; p < 4; p++) {        // K + V(transposed): 128 band rows
        int kr = trow + p * 32;
        int ka = s0 - 25 + kr;
        bool in = (ka >= 0) & (ka < SEQ);
        uint4 kv = z4, vv = z4;
        if (in) {
            kv = *(const uint4*)(qkv + (size_t)(brow0 + ka) * 3072 + 1024 + h * 64 + tc);
            vv = *(const uint4*)(qkv + (size_t)(brow0 + ka) * 3072 + 2048 + h * 64 + tc);
        }
        *(uint4*)(Ks + kr * 72 + tc) = kv;
        const unsigned short* e = (const unsigned short*)&vv;
        #pragma unroll
        for (int j = 0; j < 8; j++)
            Vt[(tc + j) * 168 + kr] = e[j];
    }
    if (t < 176) {
        float4 f = ((const float4*)rel)[t];
        int fi = t * 4, rr = fi >> 6, cc = fi & 63;
        ushort4 u;
        u.x = f2bf(f.x); u.y = f2bf(f.y); u.z = f2bf(f.z); u.w = f2bf(f.w);
        *(ushort4*)(Rs + rr * 72 + cc) = u;
    } else {
        int fi = 704 + (t - 176) * 4, rr = fi >> 6, cc = fi & 63;
        *(ushort4*)(Rs + rr * 72 + cc) = make_ushort4(0, 0, 0, 0);
    }
    {
        int n = t * 4, w2 = n >> 8, rem = n & 255, rr = rem >> 4, cc = 80 + (rem & 15);
        *(ushort4*)(Pl + w2 * (16 * 104) + rr * 104 + cc) = make_ushort4(0, 0, 0, 0);
    }
    for (int idx = t; idx < 320; idx += 256) {
        int r = idx / 5, cchunk = idx % 5;
        *(uint4*)(Vt + r * 168 + 128 + cchunk * 8) = z4;
    }
    __syncthreads();

    const int wave = t >> 6;
    const int lane = t & 63;
    const int fm   = lane & 15;
    const int fk8  = (lane >> 4) * 8;
    const int S0w  = s0 + wave * 16;
    unsigned short* Plw = Pl + wave * (16 * 104);
    float* Ql = Qrl + wave * (16 * 12);

    bf16x8 qa0 = *(const bf16x8*)(Qs + (wave * 16 + fm) * 72 + fk8);
    bf16x8 qa1 = *(const bf16x8*)(Qs + (wave * 16 + fm) * 72 + fk8 + 32);

    floatx4 Sc[5];
    #pragma unroll
    for (int nt = 0; nt < 5; nt++) {
        bf16x8 kb0 = *(const bf16x8*)(Ks + (wave * 16 + nt * 16 + fm) * 72 + fk8);
        bf16x8 kb1 = *(const bf16x8*)(Ks + (wave * 16 + nt * 16 + fm) * 72 + fk8 + 32);
        floatx4 acc = {0.f, 0.f, 0.f, 0.f};
        acc = __builtin_amdgcn_mfma_f32_16x16x32_bf16(qa0, kb0, acc, 0, 0, 0);
        acc = __builtin_amdgcn_mfma_f32_16x16x32_bf16(qa1, kb1, acc, 0, 0, 0);
        Sc[nt] = acc;
    }
    {
        bf16x8 rb0 = *(const bf16x8*)(Rs + fm * 72 + fk8);
        bf16x8 rb1 = *(const bf16x8*)(Rs + fm * 72 + fk8 + 32);
        floatx4 qr = {0.f, 0.f, 0.f, 0.f};
        qr = __builtin_amdgcn_mfma_f32_16x16x32_bf16(qa0, rb0, qr, 0, 0, 0);
        qr = __builtin_amdgcn_mfma_f32_16x16x32_bf16(qa1, rb1, qr, 0, 0, 0);
        if (fm < 12) {
            #pragma unroll
            for (int reg = 0; reg < 4; reg++)
                Ql[((lane >> 4) * 4 + reg) * 12 + fm] = qr[reg];
        }
    }

    float inv[4];
    const int iq0 = (lane >> 4) * 4;
    #pragma unroll
    for (int reg = 0; reg < 4; reg++) {
        const int i = iq0 + reg;
        float sc[5];
        float mx = -1e30f;
        #pragma unroll
        for (int nt = 0; nt < 5; nt++) {
            int c   = nt * 16 + fm;
            int off = c - 25 - i;
            int ka  = S0w - 25 + c;
            bool valid = (off >= -RAD) & (off <= RAD) & (ka >= 0) & (ka < SEQ);
            int rid = min(max(off, -5), 5) + 5;
            float v = valid ? (Sc[nt][reg] + Ql[i * 12 + rid]) * 0.125f : -1e30f;
            sc[nt] = v;
            mx = fmaxf(mx, v);
        }
        #pragma unroll
        for (int o = 1; o < 16; o <<= 1) mx = fmaxf(mx, __shfl_xor(mx, o));
        float sum = 0.f;
        #pragma unroll
        for (int nt = 0; nt < 5; nt++) {
            float e = __expf(sc[nt] - mx);
            sum += e;
            Plw[i * 104 + nt * 16 + fm] = f2bf(e);
        }
        #pragma unroll
        for (int o = 1; o < 16; o <<= 1) sum += __shfl_xor(sum, o);
        inv[reg] = 1.0f / sum;
    }

    floatx4 O[4] = {};
    #pragma unroll
    for (int kc = 0; kc < 3; kc++) {
        bf16x8 pa = *(const bf16x8*)(Plw + fm * 104 + fk8 + kc * 32);
        #pragma unroll
        for (int nt = 0; nt < 4; nt++) {
            bf16x8 vb = *(const bf16x8*)(Vt + (nt * 16 + fm) * 168 + wave * 16 + fk8 + kc * 32);
            O[nt] = __builtin_amdgcn_mfma_f32_16x16x32_bf16(pa, vb, O[nt], 0, 0, 0);
        }
    }

    #pragma unroll
    for (int nt = 0; nt < 4; nt++) {
        const int d = nt * 16 + fm;
        #pragma unroll
        for (int reg = 0; reg < 4; reg++) {
            const int i = iq0 + reg;
            attnb[(size_t)(brow0 + S0w + i) * 1024 + h * 64 + d] = f2bf(O[nt][reg] * inv[reg]);
        }
    }
}

// ---------------------------------------------------------------------------
// Fused (residual + bf16 K-slice partials + column bias) + LayerNorm.
// ---------------------------------------------------------------------------
__global__ __launch_bounds__(256)
void ln_fuse(const float* __restrict__ resf,
             const unsigned short* __restrict__ resb,
             const unsigned short* __restrict__ p0,
             const unsigned short* __restrict__ p1,
             const float* __restrict__ cbias,
             const float* __restrict__ gamma,
             const float* __restrict__ beta,
             float* __restrict__ outf,
             unsigned short* __restrict__ outb)
{
    const int wave = threadIdx.x >> 6;
    const int lane = threadIdx.x & 63;
    const int row = blockIdx.x * 4 + wave;
    const size_t base = (size_t)row * D_MODEL;

    float x[16];
    float sum = 0.0f, sq = 0.0f;
    #pragma unroll
    for (int i = 0; i < 4; i++) {
        const int c4 = lane + i * 64;
        ushort4 u0 = ((const ushort4*)(p0 + base))[c4];
        ushort4 u1 = ((const ushort4*)(p1 + base))[c4];
        float4 cb = ((const float4*)cbias)[c4];
        float4 va;
        if (resf) {
            va = ((const float4*)(resf + base))[c4];
        } else {
            ushort4 ua = ((const ushort4*)(resb + base))[c4];
            va.x = bf2f(ua.x); va.y = bf2f(ua.y); va.z = bf2f(ua.z); va.w = bf2f(ua.w);
        }
        float e0 = va.x + bf2f(u0.x) + bf2f(u1.x) + cb.x;
        float e1 = va.y + bf2f(u0.y) + bf2f(u1.y) + cb.y;
        float e2 = va.z + bf2f(u0.z) + bf2f(u1.z) + cb.z;
        float e3 = va.w + bf2f(u0.w) + bf2f(u1.w) + cb.w;
        x[i*4+0] = e0; x[i*4+1] = e1; x[i*4+2] = e2; x[i*4+3] = e3;
        sum += e0 + e1 + e2 + e3;
        sq  += e0*e0 + e1*e1 + e2*e2 + e3*e3;
    }
    #pragma unroll
    for (int off = 32; off > 0; off >>= 1) {
        sum += __shfl_xor(sum, off);
        sq  += __shfl_xor(sq,  off);
    }
    const float mean = sum * (1.0f / 1024.0f);
    const float var  = sq  * (1.0f / 1024.0f) - mean * mean;
    const float rs   = rsqrtf(var + 1e-5f);

    #pragma unroll
    for (int i = 0; i < 4; i++) {
        const int c4 = lane + i * 64;
        float4 g4 = ((const float4*)gamma)[c4];
        float4 b4 = ((const float4*)beta)[c4];
        float4 o;
        o.x = (x[i*4+0] - mean) * rs * g4.x + b4.x;
        o.y = (x[i*4+1] - mean) * rs * g4.y + b4.y;
        o.z = (x[i*4+2] - mean) * rs * g4.z + b4.z;
        o.w = (x[i*4+3] - mean) * rs * g4.w + b4.w;
        if (outf) ((float4*)(outf + base))[c4] = o;
        if (outb) {
            ushort4 u;
            u.x = f2bf(o.x); u.y = f2bf(o.y); u.z = f2bf(o.z); u.w = f2bf(o.w);
            ((ushort4*)(outb + base))[c4] = u;
        }
    }
}

// ---------------------------------------------------------------------------
extern "C" void kernel_launch(void* const* d_in, const int* in_sizes, int n_in,
                              void* d_out, int out_size, void* d_ws, size_t ws_size,
                              hipStream_t stream)
{
    const float* src = (const float*)d_in[0];
    const float* wq  = (const float*)d_in[1];
    const float* bq  = (const float*)d_in[2];
    const float* wk  = (const float*)d_in[3];
    const float* bk  = (const float*)d_in[4];
    const float* wv  = (const float*)d_in[5];
    const float* bv  = (const float*)d_in[6];
    const float* wo  = (const float*)d_in[7];
    const float* bo  = (const float*)d_in[8];
    const float* rel = (const float*)d_in[9];
    const float* w1  = (const float*)d_in[10];
    const float* b1  = (const float*)d_in[11];
    const float* w2  = (const float*)d_in[12];
    const float* b2  = (const float*)d_in[13];
    const float* g1  = (const float*)d_in[14];
    const float* be1 = (const float*)d_in[15];
    const float* g2  = (const float*)d_in[16];
    const float* be2 = (const float*)d_in[17];
    float* out = (float*)d_out;

    char* ws = (char*)d_ws;
    const size_t MB = 1048576;
    unsigned short* wqkvb = (unsigned short*)(ws + 0);        //  6 MB
    unsigned short* wob   = (unsigned short*)(ws + 6  * MB);  //  2 MB
    unsigned short* w1b   = (unsigned short*)(ws + 8  * MB);  //  8 MB
    unsigned short* w2b   = (unsigned short*)(ws + 16 * MB);  //  8 MB
    float*          bqkv  = (float*)         (ws + 24 * MB);  // 12 KB
    unsigned short* xb    = (unsigned short*)(ws + 25 * MB);  //  8 MB (dead after QKV)
    unsigned short* attnb = (unsigned short*)(ws + 25 * MB);  //  reuse xb
    unsigned short* qkvb  = (unsigned short*)(ws + 33 * MB);  // 24 MB (dead after attn)
    unsigned short* z01   = (unsigned short*)(ws + 33 * MB);  // 16 MB: WO partials
    unsigned short* ff1b  = (unsigned short*)(ws + 33 * MB);  // 32 MB (after LN1)
    unsigned short* f01   = (unsigned short*)(ws + 65 * MB);  // 16 MB: FF2 partials
    unsigned short* x1b   = (unsigned short*)(ws + 81 * MB);  //  8 MB (ends 89)
    const size_t SL = (size_t)NROWS * 1024;                   // partial slice elems

    const dim3 blk(256);
    // all conversions + bias concat in one launch (4,194,496 float4 groups)
    cvt_all<<<16385, blk, 0, stream>>>(src, wq, wk, wv, wo, w1, w2, bq, bk, bv,
                                       xb, wqkvb, wob, w1b, w2b, bqkv);
    // QKV: 4096x3072, K=1024, no split (T=768)
    gemm_bt<<<768, blk, 0, stream>>>(xb, wqkvb, bqkv, qkvb, 1024, 1024, 768, 3072, 0);
    // windowed attention
    attn_mfma<<<1024, blk, 0, stream>>>(qkvb, rel, attnb);
    // WO: 4096x1024, K=1024 split 2 -> bf16 partials z01 (T=256, grid 512)
    gemm_bt<<<512, blk, 0, stream>>>(attnb, wob, nullptr, z01, 1024, 512, 256, 1024, 0);
    // x1 = LN(src + z0 + z1 + bo)
    ln_fuse<<<NROWS / 4, blk, 0, stream>>>(src, nullptr, z01, z01 + SL, bo, g1, be1,
                                           nullptr, x1b);
    // FF1: 4096x4096, K=1024, relu+bias (T=1024)
    gemm_bt<<<1024, blk, 0, stream>>>(x1b, w1b, b1, ff1b, 1024, 1024, 1024, 4096, 1);
    // FF2: 4096x1024, K=4096 split 2 -> bf16 partials f01 (T=256, grid 512)
    gemm_bt<<<512, blk, 0, stream>>>(ff1b, w2b, nullptr, f01, 4096, 2048, 256, 1024, 0);
    // out = LN(x1 + f0 + f1 + b2)
    ln_fuse<<<NROWS / 4, blk, 0, stream>>>(nullptr, x1b, f01, f01 + SL, b2, g2, be2,
                                           out, nullptr);
}

// Round 8
// 309.802 us; speedup vs baseline: 1.1872x; 1.0143x over previous
//
#include <hip/hip_runtime.h>

// ============================================================================
// ETC layer: windowed rel-pos attention + FFN, bf16 MFMA GEMMs on gfx950
//   B=2 S=2048 D_MODEL=1024 NHEAD=16 DHEAD=64 DFF=4096 R=25 W=51 K=5
// R8: revert R7's racy barrier-free pipeline (failed correctness).
//     gemm_bt = R6 barrier structure but BK=32 dbuf (32 KB LDS) +
//     __launch_bounds__(256,4) -> 4-5 blocks/CU so the per-iteration
//     vmcnt(0) barrier drain overlaps other blocks' compute (m114).
// ============================================================================

#define D_MODEL 1024
#define SEQ     2048
#define NROWS   4096      // B*S
#define WIN     51
#define RAD     25

typedef __attribute__((ext_vector_type(8))) __bf16 bf16x8;
typedef __attribute__((ext_vector_type(4))) float  floatx4;

__device__ __forceinline__ unsigned short f2bf(float x) {
    unsigned u = __float_as_uint(x);
    unsigned r = u + 0x7fffu + ((u >> 16) & 1u);
    return (unsigned short)(r >> 16);
}
__device__ __forceinline__ float bf2f(unsigned short h) {
    return __uint_as_float(((unsigned)h) << 16);
}

// async global->LDS 16B per lane; LDS dest = wave-uniform base + lane*16
__device__ __forceinline__ void gld16(const unsigned short* g, unsigned short* l) {
    __builtin_amdgcn_global_load_lds(
        (const __attribute__((address_space(1))) unsigned int*)g,
        (__attribute__((address_space(3))) unsigned int*)l,
        16, 0, 0);
}

// ---------------------------------------------------------------------------
// One-shot conversion kernel (unchanged from R6).
// ---------------------------------------------------------------------------
__device__ __forceinline__ void cvtgrp(const float* __restrict__ in,
                                       unsigned short* __restrict__ out, int g) {
    float4 f = ((const float4*)in)[g];
    ushort4 u;
    u.x = f2bf(f.x); u.y = f2bf(f.y); u.z = f2bf(f.z); u.w = f2bf(f.w);
    ((ushort4*)out)[g] = u;
}

__global__ __launch_bounds__(256)
void cvt_all(const float* __restrict__ src,
             const float* __restrict__ wq, const float* __restrict__ wk,
             const float* __restrict__ wv, const float* __restrict__ wo,
             const float* __restrict__ w1, const float* __restrict__ w2,
             const float* __restrict__ bq, const float* __restrict__ bk,
             const float* __restrict__ bv,
             unsigned short* __restrict__ xb,
             unsigned short* __restrict__ wqkvb,
             unsigned short* __restrict__ wob,
             unsigned short* __restrict__ w1b,
             unsigned short* __restrict__ w2b,
             float* __restrict__ bqkv)
{
    int g = blockIdx.x * 256 + threadIdx.x;
    if (g >= 4194496) return;
    if (g < 1048576) { cvtgrp(src, xb, g); return; }
    g -= 1048576;
    if (g < 262144) { cvtgrp(wq, wqkvb, g); return; }
    g -= 262144;
    if (g < 262144) { cvtgrp(wk, wqkvb + 1048576, g); return; }
    g -= 262144;
    if (g < 262144) { cvtgrp(wv, wqkvb + 2097152, g); return; }
    g -= 262144;
    if (g < 262144) { cvtgrp(wo, wob, g); return; }
    g -= 262144;
    if (g < 1048576) { cvtgrp(w1, w1b, g); return; }
    g -= 1048576;
    if (g < 1048576) { cvtgrp(w2, w2b, g); return; }
    g -= 1048576;
    float4 f = (g < 64) ? ((const float4*)bq)[g]
             : (g < 128) ? ((const float4*)bk)[g - 64]
                         : ((const float4*)bv)[g - 128];
    ((float4*)bqkv)[g] = f;
}

// ---------------------------------------------------------------------------
// GEMM  C[M,N] = A[M,K] @ W[N,K]^T (+bias,relu)   (bf16 in, fp32 acc)
// 128x128 tile, 4 waves (64x64 quadrants), 16x16x32 MFMA, BK=32.
// Double-buffered LDS (2 x 16 KB = 32 KB -> 4-5 blocks/CU), barrier
// structure per R4/R6: per iter: __syncthreads (vmcnt drain of cur buf) ->
// issue prefetch of next buf -> compute cur.
// Granule swizzle (4 x 16B granules per 64B row): phys p = g ^ ((row>>1)&3)
//   staging source col = ((lane&3) ^ ((lane>>3)&3))*8  (wave-uniform LDS
//   dest + lane*16 preserved; 64B-row coalescing preserved)
//   frag read granule  = (lane>>4) ^ ((fm>>1)&3)  (8 lanes/16B-slot =
//   free 2-way, same class as R4's measured-0 scheme)
// XCD-aware tile swizzle + optional split-K unchanged from R5/R6.
// ---------------------------------------------------------------------------
#define BM 128
#define BN 128
#define BK 32

__global__ __launch_bounds__(256, 4)
void gemm_bt(const unsigned short* __restrict__ A,
             const unsigned short* __restrict__ Wt,
             const float* __restrict__ bias,
             unsigned short* __restrict__ Cb,
             int kstride, int kloop, int T, int ldc, int relu)
{
    __shared__ __attribute__((aligned(16))) unsigned short As[2][BM * BK];
    __shared__ __attribute__((aligned(16))) unsigned short Bs[2][BN * BK];

    // ---- slice + XCD-aware tile decode ----
    const int id = blockIdx.x;
    const int s  = id / T;
    const int t  = id - s * T;
    const int sid  = (t & 7) * (T >> 3) + (t >> 3);  // XCD-contiguous
    const int rect = sid >> 5;                       // 4x8 tile rect
    const int r    = sid & 31;
    const int bm = ((rect & 7) * 4 + (r >> 3)) * BM;
    const int bn = ((rect >> 3) * 8 + (r & 7)) * BN;

    const int tid  = threadIdx.x;
    const int lane = tid & 63;
    const int wave = tid >> 6;
    const int wm = (wave >> 1) * 64;
    const int wn = (wave & 1) * 64;

    // staging: wave w covers rows [32w,32w+32): 2 issues x (16 rows x 64B)
    const int srow = lane >> 2;                             // 0..15
    const int scol = ((lane & 3) ^ ((lane >> 3) & 3)) * 8;  // swizzled col
    const int kofs = s * kloop;
    const unsigned short* Ag = A  + (size_t)(bm + wave * 32 + srow) * kstride + kofs + scol;
    const unsigned short* Wg = Wt + (size_t)(bn + wave * 32 + srow) * kstride + kofs + scol;
    const size_t tstep = (size_t)16 * kstride;              // +16 rows
    const int lb = wave * 1024;                             // elems

    const int fm  = lane & 15;
    const int pg8 = ((lane >> 4) ^ ((fm >> 1) & 3)) * 8;    // phys granule *8

    floatx4 acc[4][4] = {};
    const int iters = kloop >> 5;

    auto issue = [&](int j, int b) {
        const unsigned short* Aj = Ag + j * BK;
        const unsigned short* Wj = Wg + j * BK;
        gld16(Aj,         &As[b][lb]);
        gld16(Aj + tstep, &As[b][lb + 512]);
        gld16(Wj,         &Bs[b][lb]);
        gld16(Wj + tstep, &Bs[b][lb + 512]);
    };

    issue(0, 0);   // prologue: stage buf 0

    for (int j = 0; j < iters; j++) {
        const int cur = j & 1;
        __syncthreads();   // drains vmcnt(0): buf[cur] resident; prev frag
                           // ds_reads done (lgkmcnt drain) before overwrite
        if (j + 1 < iters) issue(j + 1, cur ^ 1);

        bf16x8 af[4], bf[4];
        #pragma unroll
        for (int ii = 0; ii < 4; ii++)
            af[ii] = *(const bf16x8*)(&As[cur][(wm + ii * 16 + fm) * BK + pg8]);
        #pragma unroll
        for (int jj = 0; jj < 4; jj++)
            bf[jj] = *(const bf16x8*)(&Bs[cur][(wn + jj * 16 + fm) * BK + pg8]);
        #pragma unroll
        for (int ii = 0; ii < 4; ii++)
            #pragma unroll
            for (int jj = 0; jj < 4; jj++)
                acc[ii][jj] = __builtin_amdgcn_mfma_f32_16x16x32_bf16(
                    af[ii], bf[jj], acc[ii][jj], 0, 0, 0);
    }

    unsigned short* Co = Cb + (size_t)s * NROWS * ldc;
    const int r0 = bm + wm + (lane >> 4) * 4;
    const int c0e = bn + wn + (lane & 15);
    #pragma unroll
    for (int i = 0; i < 4; i++) {
        #pragma unroll
        for (int j = 0; j < 4; j++) {
            const int col = c0e + j * 16;
            const float bv = bias ? bias[col] : 0.0f;
            #pragma unroll
            for (int rr = 0; rr < 4; rr++) {
                const int row = r0 + i * 16 + rr;
                float v = acc[i][j][rr] + bv;
                if (relu) v = fmaxf(v, 0.0f);
                Co[(size_t)row * ldc + col] = f2bf(v);
            }
        }
    }
}

// ---------------------------------------------------------------------------
// Banded MFMA windowed attention (unchanged from R2).
// ---------------------------------------------------------------------------
__global__ __launch_bounds__(256, 2)
void attn_mfma(const unsigned short* __restrict__ qkv,   // (B*S) x 3072 bf16
               const float* __restrict__ rel,            // 11 x 64 fp32
               unsigned short* __restrict__ attnb)       // (B*S) x 1024 bf16
{
    __shared__ __attribute__((aligned(16))) unsigned short Qs[64 * 72];
    __shared__ __attribute__((aligned(16))) unsigned short Ks[128 * 72];
    __shared__ __attribute__((aligned(16))) unsigned short Vt[64 * 168];
    __shared__ __attribute__((aligned(16))) unsigned short Rs[16 * 72];
    __shared__ __attribute__((aligned(16))) unsigned short Pl[4 * 16 * 104];
    __shared__ float Qrl[4 * 16 * 12];

    const int t   = threadIdx.x;
    const int blk = blockIdx.x;          // ((b*16 + h)*32 + st)
    const int st  = blk & 31;
    const int h   = (blk >> 5) & 15;
    const int b   = blk >> 9;
    const int s0  = st << 6;
    const int brow0 = b * SEQ;

    const int trow = t >> 3;             // 0..31
    const int tc   = (t & 7) * 8;        // 0,8,..,56
    const uint4 z4 = make_uint4(0, 0, 0, 0);

    #pragma unroll
    for (int p = 0; p < 2; p++) {        // Q: 64 x 64
        int r = trow + p * 32;
        uint4 v = *(const uint4*)(qkv + (size_t)(brow0 + s0 + r) * 3072 + h * 64 + tc);
        *(uint4*)(Qs + r * 72 + tc) = v;
    }
    #pragma unroll
    for (int p = 0; p < 4; p++) {        // K + V(transposed): 128 band rows
        int kr = trow + p * 32;
        int ka = s0 - 25 + kr;
        bool in = (ka >= 0) & (ka < SEQ);
        uint4 kv = z4, vv = z4;
        if (in) {
            kv = *(const uint4*)(qkv + (size_t)(brow0 + ka) * 3072 + 1024 + h * 64 + tc);
            vv = *(const uint4*)(qkv + (size_t)(brow0 + ka) * 3072 + 2048 + h * 64 + tc);
        }
        *(uint4*)(Ks + kr * 72 + tc) = kv;
        const unsigned short* e = (const unsigned short*)&vv;
        #pragma unroll
        for (int j = 0; j < 8; j++)
            Vt[(tc + j) * 168 + kr] = e[j];
    }
    if (t < 176) {
        float4 f = ((const float4*)rel)[t];
        int fi = t * 4, rr = fi >> 6, cc = fi & 63;
        ushort4 u;
        u.x = f2bf(f.x); u.y = f2bf(f.y); u.z = f2bf(f.z); u.w = f2bf(f.w);
        *(ushort4*)(Rs + rr * 72 + cc) = u;
    } else {
        int fi = 704 + (t - 176) * 4, rr = fi >> 6, cc = fi & 63;
        *(ushort4*)(Rs + rr * 72 + cc) = make_ushort4(0, 0, 0, 0);
    }
    {
        int n = t * 4, w2 = n >> 8, rem = n & 255, rr = rem >> 4, cc = 80 + (rem & 15);
        *(ushort4*)(Pl + w2 * (16 * 104) + rr * 104 + cc) = make_ushort4(0, 0, 0, 0);
    }
    for (int idx = t; idx < 320; idx += 256) {
        int r = idx / 5, cchunk = idx % 5;
        *(uint4*)(Vt + r * 168 + 128 + cchunk * 8) = z4;
    }
    __syncthreads();

    const int wave = t >> 6;
    const int lane = t & 63;
    const int fm   = lane & 15;
    const int fk8  = (lane >> 4) * 8;
    const int S0w  = s0 + wave * 16;
    unsigned short* Plw = Pl + wave * (16 * 104);
    float* Ql = Qrl + wave * (16 * 12);

    bf16x8 qa0 = *(const bf16x8*)(Qs + (wave * 16 + fm) * 72 + fk8);
    bf16x8 qa1 = *(const bf16x8*)(Qs + (wave * 16 + fm) * 72 + fk8 + 32);

    floatx4 Sc[5];
    #pragma unroll
    for (int nt = 0; nt < 5; nt++) {
        bf16x8 kb0 = *(const bf16x8*)(Ks + (wave * 16 + nt * 16 + fm) * 72 + fk8);
        bf16x8 kb1 = *(const bf16x8*)(Ks + (wave * 16 + nt * 16 + fm) * 72 + fk8 + 32);
        floatx4 acc = {0.f, 0.f, 0.f, 0.f};
        acc = __builtin_amdgcn_mfma_f32_16x16x32_bf16(qa0, kb0, acc, 0, 0, 0);
        acc = __builtin_amdgcn_mfma_f32_16x16x32_bf16(qa1, kb1, acc, 0, 0, 0);
        Sc[nt] = acc;
    }
    {
        bf16x8 rb0 = *(const bf16x8*)(Rs + fm * 72 + fk8);
        bf16x8 rb1 = *(const bf16x8*)(Rs + fm * 72 + fk8 + 32);
        floatx4 qr = {0.f, 0.f, 0.f, 0.f};
        qr = __builtin_amdgcn_mfma_f32_16x16x32_bf16(qa0, rb0, qr, 0, 0, 0);
        qr = __builtin_amdgcn_mfma_f32_16x16x32_bf16(qa1, rb1, qr, 0, 0, 0);
        if (fm < 12) {
            #pragma unroll
            for (int reg = 0; reg < 4; reg++)
                Ql[((lane >> 4) * 4 + reg) * 12 + fm] = qr[reg];
        }
    }

    float inv[4];
    const int iq0 = (lane >> 4) * 4;
    #pragma unroll
    for (int reg = 0; reg < 4; reg++) {
        const int i = iq0 + reg;
        float sc[5];
        float mx = -1e30f;
        #pragma unroll
        for (int nt = 0; nt < 5; nt++) {
            int c   = nt * 16 + fm;
            int off = c - 25 - i;
            int ka  = S0w - 25 + c;
            bool valid = (off >= -RAD) & (off <= RAD) & (ka >= 0) & (ka < SEQ);
            int rid = min(max(off, -5), 5) + 5;
            float v = valid ? (Sc[nt][reg] + Ql[i * 12 + rid]) * 0.125f : -1e30f;
            sc[nt] = v;
            mx = fmaxf(mx, v);
        }
        #pragma unroll
        for (int o = 1; o < 16; o <<= 1) mx = fmaxf(mx, __shfl_xor(mx, o));
        float sum = 0.f;
        #pragma unroll
        for (int nt = 0; nt < 5; nt++) {
            float e = __expf(sc[nt] - mx);
            sum += e;
            Plw[i * 104 + nt * 16 + fm] = f2bf(e);
        }
        #pragma unroll
        for (int o = 1; o < 16; o <<= 1) sum += __shfl_xor(sum, o);
        inv[reg] = 1.0f / sum;
    }

    floatx4 O[4] = {};
    #pragma unroll
    for (int kc = 0; kc < 3; kc++) {
        bf16x8 pa = *(const bf16x8*)(Plw + fm * 104 + fk8 + kc * 32);
        #pragma unroll
        for (int nt = 0; nt < 4; nt++) {
            bf16x8 vb = *(const bf16x8*)(Vt + (nt * 16 + fm) * 168 + wave * 16 + fk8 + kc * 32);
            O[nt] = __builtin_amdgcn_mfma_f32_16x16x32_bf16(pa, vb, O[nt], 0, 0, 0);
        }
    }

    #pragma unroll
    for (int nt = 0; nt < 4; nt++) {
        const int d = nt * 16 + fm;
        #pragma unroll
        for (int reg = 0; reg < 4; reg++) {
            const int i = iq0 + reg;
            attnb[(size_t)(brow0 + S0w + i) * 1024 + h * 64 + d] = f2bf(O[nt][reg] * inv[reg]);
        }
    }
}

// ---------------------------------------------------------------------------
// Fused (residual + bf16 K-slice partials + column bias) + LayerNorm.
// ---------------------------------------------------------------------------
__global__ __launch_bounds__(256)
void ln_fuse(const float* __restrict__ resf,
             const unsigned short* __restrict__ resb,
             const unsigned short* __restrict__ p0,
             const unsigned short* __restrict__ p1,
             const float* __restrict__ cbias,
             const float* __restrict__ gamma,
             const float* __restrict__ beta,
             float* __restrict__ outf,
             unsigned short* __restrict__ outb)
{
    const int wave = threadIdx.x >> 6;
    const int lane = threadIdx.x & 63;
    const int row = blockIdx.x * 4 + wave;
    const size_t base = (size_t)row * D_MODEL;

    float x[16];
    float sum = 0.0f, sq = 0.0f;
    #pragma unroll
    for (int i = 0; i < 4; i++) {
        const int c4 = lane + i * 64;
        ushort4 u0 = ((const ushort4*)(p0 + base))[c4];
        ushort4 u1 = ((const ushort4*)(p1 + base))[c4];
        float4 cb = ((const float4*)cbias)[c4];
        float4 va;
        if (resf) {
            va = ((const float4*)(resf + base))[c4];
        } else {
            ushort4 ua = ((const ushort4*)(resb + base))[c4];
            va.x = bf2f(ua.x); va.y = bf2f(ua.y); va.z = bf2f(ua.z); va.w = bf2f(ua.w);
        }
        float e0 = va.x + bf2f(u0.x) + bf2f(u1.x) + cb.x;
        float e1 = va.y + bf2f(u0.y) + bf2f(u1.y) + cb.y;
        float e2 = va.z + bf2f(u0.z) + bf2f(u1.z) + cb.z;
        float e3 = va.w + bf2f(u0.w) + bf2f(u1.w) + cb.w;
        x[i*4+0] = e0; x[i*4+1] = e1; x[i*4+2] = e2; x[i*4+3] = e3;
        sum += e0 + e1 + e2 + e3;
        sq  += e0*e0 + e1*e1 + e2*e2 + e3*e3;
    }
    #pragma unroll
    for (int off = 32; off > 0; off >>= 1) {
        sum += __shfl_xor(sum, off);
        sq  += __shfl_xor(sq,  off);
    }
    const float mean = sum * (1.0f / 1024.0f);
    const float var  = sq  * (1.0f / 1024.0f) - mean * mean;
    const float rs   = rsqrtf(var + 1e-5f);

    #pragma unroll
    for (int i = 0; i < 4; i++) {
        const int c4 = lane + i * 64;
        float4 g4 = ((const float4*)gamma)[c4];
        float4 b4 = ((const float4*)beta)[c4];
        float4 o;
        o.x = (x[i*4+0] - mean) * rs * g4.x + b4.x;
        o.y = (x[i*4+1] - mean) * rs * g4.y + b4.y;
        o.z = (x[i*4+2] - mean) * rs * g4.z + b4.z;
        o.w = (x[i*4+3] - mean) * rs * g4.w + b4.w;
        if (outf) ((float4*)(outf + base))[c4] = o;
        if (outb) {
            ushort4 u;
            u.x = f2bf(o.x); u.y = f2bf(o.y); u.z = f2bf(o.z); u.w = f2bf(o.w);
            ((ushort4*)(outb + base))[c4] = u;
        }
    }
}

// ---------------------------------------------------------------------------
extern "C" void kernel_launch(void* const* d_in, const int* in_sizes, int n_in,
                              void* d_out, int out_size, void* d_ws, size_t ws_size,
                              hipStream_t stream)
{
    const float* src = (const float*)d_in[0];
    const float* wq  = (const float*)d_in[1];
    const float* bq  = (const float*)d_in[2];
    const float* wk  = (const float*)d_in[3];
    const float* bk  = (const float*)d_in[4];
    const float* wv  = (const float*)d_in[5];
    const float* bv  = (const float*)d_in[6];
    const float* wo  = (const float*)d_in[7];
    const float* bo  = (const float*)d_in[8];
    const float* rel = (const float*)d_in[9];
    const float* w1  = (const float*)d_in[10];
    const float* b1  = (const float*)d_in[11];
    const float* w2  = (const float*)d_in[12];
    const float* b2  = (const float*)d_in[13];
    const float* g1  = (const float*)d_in[14];
    const float* be1 = (const float*)d_in[15];
    const float* g2  = (const float*)d_in[16];
    const float* be2 = (const float*)d_in[17];
    float* out = (float*)d_out;

    char* ws = (char*)d_ws;
    const size_t MB = 1048576;
    unsigned short* wqkvb = (unsigned short*)(ws + 0);        //  6 MB
    unsigned short* wob   = (unsigned short*)(ws + 6  * MB);  //  2 MB
    unsigned short* w1b   = (unsigned short*)(ws + 8  * MB);  //  8 MB
    unsigned short* w2b   = (unsigned short*)(ws + 16 * MB);  //  8 MB
    float*          bqkv  = (float*)         (ws + 24 * MB);  // 12 KB
    unsigned short* xb    = (unsigned short*)(ws + 25 * MB);  //  8 MB (dead after QKV)
    unsigned short* attnb = (unsigned short*)(ws + 25 * MB);  //  reuse xb
    unsigned short* qkvb  = (unsigned short*)(ws + 33 * MB);  // 24 MB (dead after attn)
    unsigned short* z01   = (unsigned short*)(ws + 33 * MB);  // 16 MB: WO partials
    unsigned short* ff1b  = (unsigned short*)(ws + 33 * MB);  // 32 MB (after LN1)
    unsigned short* f01   = (unsigned short*)(ws + 65 * MB);  // 16 MB: FF2 partials
    unsigned short* x1b   = (unsigned short*)(ws + 81 * MB);  //  8 MB (ends 89)
    const size_t SL = (size_t)NROWS * 1024;                   // partial slice elems

    const dim3 blk(256);
    cvt_all<<<16385, blk, 0, stream>>>(src, wq, wk, wv, wo, w1, w2, bq, bk, bv,
                                       xb, wqkvb, wob, w1b, w2b, bqkv);
    // QKV: 4096x3072, K=1024, no split (T=768)
    gemm_bt<<<768, blk, 0, stream>>>(xb, wqkvb, bqkv, qkvb, 1024, 1024, 768, 3072, 0);
    attn_mfma<<<1024, blk, 0, stream>>>(qkvb, rel, attnb);
    // WO: 4096x1024, K=1024 split 2 -> bf16 partials z01 (T=256, grid 512)
    gemm_bt<<<512, blk, 0, stream>>>(attnb, wob, nullptr, z01, 1024, 512, 256, 1024, 0);
    // x1 = LN(src + z0 + z1 + bo)
    ln_fuse<<<NROWS / 4, blk, 0, stream>>>(src, nullptr, z01, z01 + SL, bo, g1, be1,
                                           nullptr, x1b);
    // FF1: 4096x4096, K=1024, relu+bias (T=1024)
    gemm_bt<<<1024, blk, 0, stream>>>(x1b, w1b, b1, ff1b, 1024, 1024, 1024, 4096, 1);
    // FF2: 4096x1024, K=4096 split 2 -> bf16 partials f01 (T=256, grid 512)
    gemm_bt<<<512, blk, 0, stream>>>(ff1b, w2b, nullptr, f01, 4096, 2048, 256, 1024, 0);
    // out = LN(x1 + f0 + f1 + b2)
    ln_fuse<<<NROWS / 4, blk, 0, stream>>>(nullptr, x1b, f01, f01 + SL, b2, g2, be2,
                                           out, nullptr);
}